// Round 8
// baseline (748.805 us; speedup 1.0000x reference)
//
#include <hip/hip_runtime.h>
#include <cstdint>
#include <cstddef>

#define IN_DIM 128
#define HID    512

typedef unsigned int   uint32;
typedef unsigned short u16;
typedef __attribute__((ext_vector_type(8))) short bf16x8;   // 8 bf16 (4 VGPRs)
typedef __attribute__((ext_vector_type(4))) float f32x4;

static inline int imin_h(int a, int b) { return a < b ? a : b; }

// ---- bf16 helpers (storage-only bf16; accumulation fp32) ----
__device__ __forceinline__ float bfu2f(uint32 u) { return __uint_as_float(u << 16); }
__device__ __forceinline__ u16 f2bf(float f) {
  uint32 x = __float_as_uint(f);
  x += 0x7fffu + ((x >> 16) & 1u);           // round-to-nearest-even
  return (u16)(x >> 16);
}
__device__ __forceinline__ uint32 pack2(float a, float b) {
  return (uint32)f2bf(a) | ((uint32)f2bf(b) << 16);
}

#define GLOBAL_AS(p) ((const __attribute__((address_space(1))) void*)(p))
#define LDS_AS(p)    ((__attribute__((address_space(3))) void*)(p))

// ---------------- misc ----------------
__global__ void k_zero(int* __restrict__ p, int n) {
  for (int i = blockIdx.x * blockDim.x + threadIdx.x; i < n; i += gridDim.x * blockDim.x)
    p[i] = 0;
}

// ---------------- CSR build (by dst) ----------------
__global__ void k_hist(const int* __restrict__ dst, int* __restrict__ deg, int E) {
  for (int e = blockIdx.x * blockDim.x + threadIdx.x; e < E; e += gridDim.x * blockDim.x)
    atomicAdd(&deg[dst[e]], 1);
}

__global__ __launch_bounds__(1024)
void k_scan(const int* __restrict__ deg, int* __restrict__ rowptr, int* __restrict__ cursor, int n) {
  __shared__ int sm[1024];
  __shared__ int carry;
  const int tid = threadIdx.x;
  if (tid == 0) carry = 0;
  __syncthreads();
  for (int base = 0; base < n; base += 1024) {
    const int i = base + tid;
    const int v = (i < n) ? deg[i] : 0;
    sm[tid] = v;
    __syncthreads();
    for (int off = 1; off < 1024; off <<= 1) {
      int t = (tid >= off) ? sm[tid - off] : 0;
      __syncthreads();
      sm[tid] += t;
      __syncthreads();
    }
    const int excl = sm[tid] - v;
    if (i < n) { const int r = carry + excl; rowptr[i] = r; cursor[i] = r; }
    __syncthreads();
    if (tid == 1023) carry += sm[1023];
    __syncthreads();
  }
  if (tid == 0) rowptr[n] = carry;
}

__global__ void k_fill(const int* __restrict__ src, const int* __restrict__ dst,
                       int* __restrict__ cursor, int* __restrict__ col, int E) {
  for (int e = blockIdx.x * blockDim.x + threadIdx.x; e < E; e += gridDim.x * blockDim.x) {
    const int p = atomicAdd(&cursor[dst[e]], 1);
    col[p] = src[e];
  }
}

// ---------------- h0 = bf16(attr); masked rows = token ----------------
__global__ void k_cvt(const float4* __restrict__ in, uint2* __restrict__ out, int n4) {
  for (int i = blockIdx.x * blockDim.x + threadIdx.x; i < n4; i += gridDim.x * blockDim.x) {
    const float4 v = in[i];
    out[i] = make_uint2(pack2(v.x, v.y), pack2(v.z, v.w));
  }
}

__global__ void k_mask(const float4* __restrict__ token, const int* __restrict__ mask,
                       uint2* __restrict__ h0, int NM) {
  const int total = NM * (IN_DIM / 4);
  for (int i = blockIdx.x * blockDim.x + threadIdx.x; i < total; i += gridDim.x * blockDim.x) {
    const int m = i >> 5;
    const int c = i & 31;
    const float4 t = token[c];
    h0[(size_t)mask[m] * (IN_DIM / 4) + c] = make_uint2(pack2(t.x, t.y), pack2(t.z, t.w));
  }
}

// ---------------- weight transpose + convert: Wt[n*K+k] = bf16(W[k*N+n]) ----------------
__global__ void k_wt(const float* __restrict__ W, u16* __restrict__ Wt, int K, int Nn) {
  const int total = K * Nn;
  for (int t = blockIdx.x * blockDim.x + threadIdx.x; t < total; t += gridDim.x * blockDim.x) {
    const int n = t / K, k = t - n * K;
    Wt[t] = f2bf(W[(size_t)k * Nn + n]);
  }
}

// ---------------- mean aggregation over in-neighbors (CSR gather, 1 wave/node) ----------
template <int D>
__global__ __launch_bounds__(256)
void k_agg(const u16* __restrict__ h, const int* __restrict__ col,
           const int* __restrict__ rowptr, u16* __restrict__ out, int n) {
  constexpr int V = D / 64;  // bf16 per lane: 8 (D=512) or 2 (D=128)
  const int w = blockIdx.x * (blockDim.x >> 6) + (threadIdx.x >> 6);
  if (w >= n) return;
  const int lane = threadIdx.x & 63;
  const int beg = rowptr[w], end = rowptr[w + 1];
  const size_t loff = (size_t)lane * V;
  float acc[V];
#pragma unroll
  for (int j = 0; j < V; ++j) acc[j] = 0.f;
  for (int e = beg; e < end; ++e) {
    const u16* row = h + (size_t)col[e] * D + loff;
    if constexpr (V == 8) {
      const uint4 u = *reinterpret_cast<const uint4*>(row);
      acc[0] += bfu2f(u.x & 0xffffu); acc[1] += bfu2f(u.x >> 16);
      acc[2] += bfu2f(u.y & 0xffffu); acc[3] += bfu2f(u.y >> 16);
      acc[4] += bfu2f(u.z & 0xffffu); acc[5] += bfu2f(u.z >> 16);
      acc[6] += bfu2f(u.w & 0xffffu); acc[7] += bfu2f(u.w >> 16);
    } else {
      const uint32 u = *reinterpret_cast<const uint32*>(row);
      acc[0] += bfu2f(u & 0xffffu); acc[1] += bfu2f(u >> 16);
    }
  }
  const float inv = 1.0f / fmaxf((float)(end - beg), 1.0f);
  u16* o = out + (size_t)w * D + loff;
  if constexpr (V == 8) {
    uint4 u;
    u.x = pack2(acc[0] * inv, acc[1] * inv);
    u.y = pack2(acc[2] * inv, acc[3] * inv);
    u.z = pack2(acc[4] * inv, acc[5] * inv);
    u.w = pack2(acc[6] * inv, acc[7] * inv);
    *reinterpret_cast<uint4*>(o) = u;
  } else {
    *reinterpret_cast<uint32*>(o) = pack2(acc[0] * inv, acc[1] * inv);
  }
}

// ---------------- dual-A bf16 MFMA GEMM, 3-deep pipelined (counted vmcnt) --------------
// out = bf16(A1@W1 + A2@W2 + b), opt ReLU.
// A1,A2: M x DIN bf16 row-major. Wt1,Wt2: DOUT x DIN bf16 (transposed weights).
// 128x128 tile, BK=32, 4 waves (2x2). LDS fragment-linear, 3 rotating 16KB buffers
// (48KB -> 3 blocks/CU). Prefetch 2 steps ahead; vmcnt(8/4/0) counted (4 loads/wave/stage).
// grid = (DOUT/128, ceil(M/128)); bijective XCD swizzle (m204), n-tile fastest.
template <int DIN, int DOUT, bool RELU>
__global__ __launch_bounds__(256, 3)
void k_gemm(const u16* __restrict__ A1, const u16* __restrict__ A2,
            const u16* __restrict__ Wt1, const u16* __restrict__ Wt2,
            const float* __restrict__ bias, u16* __restrict__ out, int M) {
  __shared__ char lds[49152];                 // 3 x (A 8KB + B 8KB)
  constexpr int KS = DIN / 32;                // K-steps per phase
  constexpr int S  = 2 * KS;                  // total K-steps (dual-A)
  const int tid = threadIdx.x;
  const int w = tid >> 6, l = tid & 63;
  const int l15 = l & 15, l4 = l >> 4;
  const int wm = w >> 1, wn = w & 1;

  // bijective XCD swizzle: contiguous wg range per XCD; n-tile fastest within row-block
  const int nwg  = gridDim.x * gridDim.y;
  const int orig = blockIdx.x + gridDim.x * blockIdx.y;
  const int q = nwg >> 3, r = nwg & 7;
  const int xcd = orig & 7, seq = orig >> 3;
  const int wg = (xcd < r ? xcd * (q + 1) : r * (q + 1) + (xcd - r) * q) + seq;
  constexpr int NT = DOUT / 128;
  const int mt = wg / NT, nt = wg - mt * NT;
  const int m0 = mt * 128, n0 = nt * 128;

  f32x4 acc[4][4];
#pragma unroll
  for (int i = 0; i < 4; ++i)
#pragma unroll
    for (int j = 0; j < 4; ++j) acc[i][j] = (f32x4){0.f, 0.f, 0.f, 0.f};

  // staging: wave w stages A m-frags {2w,2w+1} and B n-frags {2w,2w+1} (4 loads/wave/step)
  const int arow0 = min(m0 + (2 * w) * 16 + l15, M - 1);
  const int arow1 = min(m0 + (2 * w + 1) * 16 + l15, M - 1);
  const int brow0 = n0 + (2 * w) * 16 + l15;
  const int brow1 = n0 + (2 * w + 1) * 16 + l15;
  const int kl = l4 * 8;                       // lane k-slice
  const u16* pA1r0 = A1  + (size_t)arow0 * DIN + kl;
  const u16* pA1r1 = A1  + (size_t)arow1 * DIN + kl;
  const u16* pA2r0 = A2  + (size_t)arow0 * DIN + kl;
  const u16* pA2r1 = A2  + (size_t)arow1 * DIN + kl;
  const u16* pW1r0 = Wt1 + (size_t)brow0 * DIN + kl;
  const u16* pW1r1 = Wt1 + (size_t)brow1 * DIN + kl;
  const u16* pW2r0 = Wt2 + (size_t)brow0 * DIN + kl;
  const u16* pW2r1 = Wt2 + (size_t)brow1 * DIN + kl;

  auto stage = [&](int s) {                    // 4 global_load_lds per wave
    const int ph = s / KS;
    const int k0 = (s - ph * KS) * 32;
    char* buf = lds + (s % 3) * 16384;
    const u16* a0 = (ph ? pA2r0 : pA1r0) + k0;
    const u16* a1 = (ph ? pA2r1 : pA1r1) + k0;
    const u16* b0 = (ph ? pW2r0 : pW1r0) + k0;
    const u16* b1 = (ph ? pW2r1 : pW1r1) + k0;
    __builtin_amdgcn_global_load_lds(GLOBAL_AS(a0), LDS_AS(buf + (2 * w + 0) * 1024), 16, 0, 0);
    __builtin_amdgcn_global_load_lds(GLOBAL_AS(a1), LDS_AS(buf + (2 * w + 1) * 1024), 16, 0, 0);
    __builtin_amdgcn_global_load_lds(GLOBAL_AS(b0), LDS_AS(buf + 8192 + (2 * w + 0) * 1024), 16, 0, 0);
    __builtin_amdgcn_global_load_lds(GLOBAL_AS(b1), LDS_AS(buf + 8192 + (2 * w + 1) * 1024), 16, 0, 0);
  };

  stage(0);
  stage(1);
  stage(2);

#pragma unroll
  for (int s = 0; s < S; ++s) {
    // wait for step s's 4 loads; steps s+1,s+2 (8 loads) stay in flight
    const int rem = S - 1 - s;
    if (rem >= 2)      asm volatile("s_waitcnt vmcnt(8)" ::: "memory");
    else if (rem == 1) asm volatile("s_waitcnt vmcnt(4)" ::: "memory");
    else               asm volatile("s_waitcnt vmcnt(0)" ::: "memory");
    __builtin_amdgcn_s_barrier();
    char* buf = lds + (s % 3) * 16384;
    bf16x8 af[4], bfr[4];
#pragma unroll
    for (int i = 0; i < 4; ++i)
      af[i] = *reinterpret_cast<const bf16x8*>(buf + (wm * 4 + i) * 1024 + l * 16);
#pragma unroll
    for (int j = 0; j < 4; ++j)
      bfr[j] = *reinterpret_cast<const bf16x8*>(buf + 8192 + (wn * 4 + j) * 1024 + l * 16);
#pragma unroll
    for (int i = 0; i < 4; ++i)
#pragma unroll
      for (int j = 0; j < 4; ++j)
        acc[i][j] = __builtin_amdgcn_mfma_f32_16x16x32_bf16(af[i], bfr[j], acc[i][j], 0, 0, 0);
    asm volatile("s_waitcnt lgkmcnt(0)" ::: "memory");   // all reads of buf retired
    __builtin_amdgcn_s_barrier();
    if (s + 3 < S) stage(s + 3);                          // refill this buffer
  }

  // epilogue: C/D mapping col = lane&15, row = (lane>>4)*4 + reg   [m89-verified]
#pragma unroll
  for (int j = 0; j < 4; ++j) {
    const int c = n0 + wn * 64 + j * 16 + l15;
    const float bv = bias[c];
#pragma unroll
    for (int i = 0; i < 4; ++i) {
      const int rowb = m0 + wm * 64 + i * 16 + l4 * 4;
#pragma unroll
      for (int r = 0; r < 4; ++r) {
        const int row = rowb + r;
        if (row < M) {
          float t = acc[i][j][r] + bv;
          if (RELU) t = fmaxf(t, 0.f);
          out[(size_t)row * DOUT + c] = f2bf(t);
        }
      }
    }
  }
}

// ---------------- loss ----------------
__global__ __launch_bounds__(256)
void k_loss1(const u16* __restrict__ dec, const float* __restrict__ attr,
             const int* __restrict__ mask, int NM, float* __restrict__ partials) {
  __shared__ float sm[256];
  float s = 0.f;
  const int total = NM * (IN_DIM / 4);
  for (int idx = blockIdx.x * blockDim.x + threadIdx.x; idx < total; idx += gridDim.x * blockDim.x) {
    const int m = idx >> 5, c = (idx & 31) * 4;
    const int node = mask[m];
    const float4 a = *reinterpret_cast<const float4*>(&attr[(size_t)node * IN_DIM + c]);
    const uint2 d2 = *reinterpret_cast<const uint2*>(&dec[(size_t)node * IN_DIM + c]);
    const float dx = bfu2f(d2.x & 0xffffu) - a.x;
    const float dy = bfu2f(d2.x >> 16)     - a.y;
    const float dz = bfu2f(d2.y & 0xffffu) - a.z;
    const float dw = bfu2f(d2.y >> 16)     - a.w;
    s += dx * dx + dy * dy + dz * dz + dw * dw;
  }
  sm[threadIdx.x] = s;
  __syncthreads();
  for (int off = 128; off > 0; off >>= 1) {
    if (threadIdx.x < off) sm[threadIdx.x] += sm[threadIdx.x + off];
    __syncthreads();
  }
  if (threadIdx.x == 0) partials[blockIdx.x] = sm[0];
}

__global__ __launch_bounds__(256)
void k_loss2(const float* __restrict__ partials, int nb, float* __restrict__ out, float inv) {
  __shared__ float sm[256];
  float s = 0.f;
  for (int i = threadIdx.x; i < nb; i += 256) s += partials[i];
  sm[threadIdx.x] = s;
  __syncthreads();
  for (int off = 128; off > 0; off >>= 1) {
    if (threadIdx.x < off) sm[threadIdx.x] += sm[threadIdx.x + off];
    __syncthreads();
  }
  if (threadIdx.x == 0) out[0] = sm[0] * inv;
}

// ---------------- launch ----------------
extern "C" void kernel_launch(void* const* d_in, const int* in_sizes, int n_in,
                              void* d_out, int out_size, void* d_ws, size_t ws_size,
                              hipStream_t stream) {
  const float* attr  = (const float*)d_in[0];
  const float* token = (const float*)d_in[1];
  const int*   src   = (const int*)d_in[2];
  const int*   dst   = (const int*)d_in[3];
  const int*   mask  = (const int*)d_in[4];
  const float* Wself[4]  = {(const float*)d_in[5], (const float*)d_in[8],
                            (const float*)d_in[11], (const float*)d_in[14]};
  const float* Wneigh[4] = {(const float*)d_in[6], (const float*)d_in[9],
                            (const float*)d_in[12], (const float*)d_in[15]};
  const float* Bias[4]   = {(const float*)d_in[7], (const float*)d_in[10],
                            (const float*)d_in[13], (const float*)d_in[16]};
  const int N  = in_sizes[0] / IN_DIM;
  const int E  = in_sizes[2];
  const int NM = in_sizes[4];

  size_t off = 0;
  auto take = [&](size_t bytes) -> void* {
    void* p = (char*)d_ws + off;
    off += (bytes + 255) & ~(size_t)255;
    return p;
  };
  u16* HA = (u16*)take((size_t)N * HID * sizeof(u16));   // 51.2 MB
  u16* HB = (u16*)take((size_t)N * HID * sizeof(u16));   // 51.2 MB
  const int dims_in[4]  = {IN_DIM, HID, HID, HID};
  const int dims_out[4] = {HID, HID, HID, IN_DIM};
  u16* WtS[4]; u16* WtN[4];
  for (int i = 0; i < 4; ++i) {
    WtS[i] = (u16*)take((size_t)dims_in[i] * dims_out[i] * sizeof(u16));
    WtN[i] = (u16*)take((size_t)dims_in[i] * dims_out[i] * sizeof(u16));
  }
  int* deg    = (int*)take((size_t)N * sizeof(int));
  int* rowptr = (int*)take((size_t)(N + 1) * sizeof(int));
  int* cursor = (int*)take((size_t)N * sizeof(int));
  int* col    = (int*)take((size_t)E * sizeof(int));
  float* partials = (float*)take(512 * sizeof(float));

  // aggregation chunk: prefer one chunk covering N (rounded up to 128 rows)
  size_t rem = (ws_size > off + 4096) ? (ws_size - off - 4096) : 0;
  const int cap = (int)(rem / ((size_t)HID * sizeof(u16)));
  const int want = (N + 127) & ~127;
  int chunk = (cap >= want) ? want : (cap & ~127);
  if (chunk < 2048) chunk = 2048;  // last-resort floor
  u16* CH = (u16*)take((size_t)chunk * HID * sizeof(u16));

  // CSR build
  k_zero<<<imin_h((N + 255) / 256, 1024), 256, 0, stream>>>(deg, N);
  const int eb = imin_h((E + 255) / 256, 4096);
  k_hist<<<eb, 256, 0, stream>>>(dst, deg, E);
  k_scan<<<1, 1024, 0, stream>>>(deg, rowptr, cursor, N);
  k_fill<<<eb, 256, 0, stream>>>(src, dst, cursor, col, E);

  // weights: transpose + bf16 once per call
  for (int i = 0; i < 4; ++i) {
    const int tot = dims_in[i] * dims_out[i];
    k_wt<<<imin_h((tot + 255) / 256, 2048), 256, 0, stream>>>(Wself[i],  WtS[i], dims_in[i], dims_out[i]);
    k_wt<<<imin_h((tot + 255) / 256, 2048), 256, 0, stream>>>(Wneigh[i], WtN[i], dims_in[i], dims_out[i]);
  }

  // h0 = bf16(attr) with masked rows = token   (in HA as N x 128)
  const int n4 = N * (IN_DIM / 4);
  k_cvt<<<imin_h((n4 + 255) / 256, 2048), 256, 0, stream>>>((const float4*)attr, (uint2*)HA, n4);
  k_mask<<<imin_h((NM * (IN_DIM / 4) + 255) / 256, 2048), 256, 0, stream>>>(
      (const float4*)token, mask, (uint2*)HA, NM);

  // per-layer chunked: agg chunk -> gemm chunk
  auto run_layer = [&](const u16* hin, u16* hout, int din, int dout, int layer, bool relu) {
    for (int c0 = 0; c0 < N; c0 += chunk) {
      const int mc = imin_h(chunk, N - c0);
      const int ab = (mc + 3) / 4;
      if (din == IN_DIM)
        k_agg<IN_DIM><<<ab, 256, 0, stream>>>(hin, col, rowptr + c0, CH, mc);
      else
        k_agg<HID><<<ab, 256, 0, stream>>>(hin, col, rowptr + c0, CH, mc);
      const u16* a1 = hin + (size_t)c0 * din;
      u16* o = hout + (size_t)c0 * dout;
      const int mb = (mc + 127) / 128;
      if (din == IN_DIM && dout == HID && relu) {
        k_gemm<IN_DIM, HID, true><<<dim3(HID / 128, mb), 256, 0, stream>>>(
            a1, CH, WtS[layer], WtN[layer], Bias[layer], o, mc);
      } else if (din == HID && dout == HID && !relu) {
        k_gemm<HID, HID, false><<<dim3(HID / 128, mb), 256, 0, stream>>>(
            a1, CH, WtS[layer], WtN[layer], Bias[layer], o, mc);
      } else if (din == HID && dout == HID && relu) {
        k_gemm<HID, HID, true><<<dim3(HID / 128, mb), 256, 0, stream>>>(
            a1, CH, WtS[layer], WtN[layer], Bias[layer], o, mc);
      } else {
        k_gemm<HID, IN_DIM, false><<<dim3(IN_DIM / 128, mb), 256, 0, stream>>>(
            a1, CH, WtS[layer], WtN[layer], Bias[layer], o, mc);
      }
    }
  };

  run_layer(HA, HB, IN_DIM, HID, 0, true);   // L1: 128->512 relu
  run_layer(HB, HA, HID,    HID, 1, false);  // L2: 512->512
  run_layer(HA, HB, HID,    HID, 2, true);   // L3: 512->512 relu
  run_layer(HB, HA, HID, IN_DIM, 3, false);  // L4: 512->128 (decoded in HA)

  // loss = mean((decoded[mask] - attr[mask])^2)
  k_loss1<<<512, 256, 0, stream>>>(HA, attr, mask, NM, partials);
  k_loss2<<<1, 256, 0, stream>>>(partials, 512, (float*)d_out, 1.0f / ((float)NM * IN_DIM));
}

// Round 9
// 699.019 us; speedup vs baseline: 1.0712x; 1.0712x over previous
//
#include <hip/hip_runtime.h>
#include <cstdint>
#include <cstddef>

#define IN_DIM 128
#define HID    512

typedef unsigned int   uint32;
typedef unsigned short u16;
typedef __attribute__((ext_vector_type(8))) short bf16x8;   // 8 bf16 (4 VGPRs)
typedef __attribute__((ext_vector_type(4))) float f32x4;

static inline int imin_h(int a, int b) { return a < b ? a : b; }

// ---- bf16 helpers (storage-only bf16; accumulation fp32) ----
__device__ __forceinline__ float bfu2f(uint32 u) { return __uint_as_float(u << 16); }
__device__ __forceinline__ u16 f2bf(float f) {
  uint32 x = __float_as_uint(f);
  x += 0x7fffu + ((x >> 16) & 1u);           // round-to-nearest-even
  return (u16)(x >> 16);
}
__device__ __forceinline__ uint32 pack2(float a, float b) {
  return (uint32)f2bf(a) | ((uint32)f2bf(b) << 16);
}

#define GLOBAL_AS(p) ((const __attribute__((address_space(1))) void*)(p))
#define LDS_AS(p)    ((__attribute__((address_space(3))) void*)(p))

// ---------------- misc ----------------
__global__ void k_zero(int* __restrict__ p, int n) {
  for (int i = blockIdx.x * blockDim.x + threadIdx.x; i < n; i += gridDim.x * blockDim.x)
    p[i] = 0;
}

// ---------------- CSR build (by dst) ----------------
__global__ void k_hist(const int* __restrict__ dst, int* __restrict__ deg, int E) {
  for (int e = blockIdx.x * blockDim.x + threadIdx.x; e < E; e += gridDim.x * blockDim.x)
    atomicAdd(&deg[dst[e]], 1);
}

__global__ __launch_bounds__(1024)
void k_scan(const int* __restrict__ deg, int* __restrict__ rowptr, int* __restrict__ cursor, int n) {
  __shared__ int sm[1024];
  __shared__ int carry;
  const int tid = threadIdx.x;
  if (tid == 0) carry = 0;
  __syncthreads();
  for (int base = 0; base < n; base += 1024) {
    const int i = base + tid;
    const int v = (i < n) ? deg[i] : 0;
    sm[tid] = v;
    __syncthreads();
    for (int off = 1; off < 1024; off <<= 1) {
      int t = (tid >= off) ? sm[tid - off] : 0;
      __syncthreads();
      sm[tid] += t;
      __syncthreads();
    }
    const int excl = sm[tid] - v;
    if (i < n) { const int r = carry + excl; rowptr[i] = r; cursor[i] = r; }
    __syncthreads();
    if (tid == 1023) carry += sm[1023];
    __syncthreads();
  }
  if (tid == 0) rowptr[n] = carry;
}

__global__ void k_fill(const int* __restrict__ src, const int* __restrict__ dst,
                       int* __restrict__ cursor, int* __restrict__ col, int E) {
  for (int e = blockIdx.x * blockDim.x + threadIdx.x; e < E; e += gridDim.x * blockDim.x) {
    const int p = atomicAdd(&cursor[dst[e]], 1);
    col[p] = src[e];
  }
}

// ---------------- h0 = bf16(attr); masked rows = token ----------------
__global__ void k_cvt(const float4* __restrict__ in, uint2* __restrict__ out, int n4) {
  for (int i = blockIdx.x * blockDim.x + threadIdx.x; i < n4; i += gridDim.x * blockDim.x) {
    const float4 v = in[i];
    out[i] = make_uint2(pack2(v.x, v.y), pack2(v.z, v.w));
  }
}

__global__ void k_mask(const float4* __restrict__ token, const int* __restrict__ mask,
                       uint2* __restrict__ h0, int NM) {
  const int total = NM * (IN_DIM / 4);
  for (int i = blockIdx.x * blockDim.x + threadIdx.x; i < total; i += gridDim.x * blockDim.x) {
    const int m = i >> 5;
    const int c = i & 31;
    const float4 t = token[c];
    h0[(size_t)mask[m] * (IN_DIM / 4) + c] = make_uint2(pack2(t.x, t.y), pack2(t.z, t.w));
  }
}

// ---------------- weight transpose + convert: Wt[n*K+k] = bf16(W[k*N+n]) ----------------
__global__ void k_wt(const float* __restrict__ W, u16* __restrict__ Wt, int K, int Nn) {
  const int total = K * Nn;
  for (int t = blockIdx.x * blockDim.x + threadIdx.x; t < total; t += gridDim.x * blockDim.x) {
    const int n = t / K, k = t - n * K;
    Wt[t] = f2bf(W[(size_t)k * Nn + n]);
  }
}

// ---------------- mean aggregation over in-neighbors (CSR gather, 1 wave/node) ----------
template <int D>
__global__ __launch_bounds__(256)
void k_agg(const u16* __restrict__ h, const int* __restrict__ col,
           const int* __restrict__ rowptr, u16* __restrict__ out, int n) {
  constexpr int V = D / 64;  // bf16 per lane: 8 (D=512) or 2 (D=128)
  const int w = blockIdx.x * (blockDim.x >> 6) + (threadIdx.x >> 6);
  if (w >= n) return;
  const int lane = threadIdx.x & 63;
  const int beg = rowptr[w], end = rowptr[w + 1];
  const size_t loff = (size_t)lane * V;
  float acc[V];
#pragma unroll
  for (int j = 0; j < V; ++j) acc[j] = 0.f;
  for (int e = beg; e < end; ++e) {
    const u16* row = h + (size_t)col[e] * D + loff;
    if constexpr (V == 8) {
      const uint4 u = *reinterpret_cast<const uint4*>(row);
      acc[0] += bfu2f(u.x & 0xffffu); acc[1] += bfu2f(u.x >> 16);
      acc[2] += bfu2f(u.y & 0xffffu); acc[3] += bfu2f(u.y >> 16);
      acc[4] += bfu2f(u.z & 0xffffu); acc[5] += bfu2f(u.z >> 16);
      acc[6] += bfu2f(u.w & 0xffffu); acc[7] += bfu2f(u.w >> 16);
    } else {
      const uint32 u = *reinterpret_cast<const uint32*>(row);
      acc[0] += bfu2f(u & 0xffffu); acc[1] += bfu2f(u >> 16);
    }
  }
  const float inv = 1.0f / fmaxf((float)(end - beg), 1.0f);
  u16* o = out + (size_t)w * D + loff;
  if constexpr (V == 8) {
    uint4 u;
    u.x = pack2(acc[0] * inv, acc[1] * inv);
    u.y = pack2(acc[2] * inv, acc[3] * inv);
    u.z = pack2(acc[4] * inv, acc[5] * inv);
    u.w = pack2(acc[6] * inv, acc[7] * inv);
    *reinterpret_cast<uint4*>(o) = u;
  } else {
    *reinterpret_cast<uint32*>(o) = pack2(acc[0] * inv, acc[1] * inv);
  }
}

// ======== dual-A bf16 MFMA GEMM, 256x256 tile, 8 waves, 4-deep counted-vmcnt pipeline ===
// out = bf16(A1@W1 + A2@W2 + b), opt ReLU.  DOUT = 512 fixed (NT = 2 n-tiles).
// A1,A2: M x DIN bf16 row-major. Wt1,Wt2: DOUT x DIN bf16 (transposed weights).
// 512 thr = 8 waves (2M x 4N); wave tile 128x64 = 8x4 frags -> 32 MFMA/step (BK=32).
// LDS fragment-linear (0 bank conflicts), 4 rotating 32KB buffers (128KB total).
// Prefetch 3 steps ahead; per-wave 4 loads/step -> vmcnt(12/8/4/0) counted.
template <int DIN, bool RELU>
__global__ __launch_bounds__(512, 2)
void k_gemm_big(const u16* __restrict__ A1, const u16* __restrict__ A2,
                const u16* __restrict__ Wt1, const u16* __restrict__ Wt2,
                const float* __restrict__ bias, u16* __restrict__ out, int M) {
  constexpr int DOUT = HID;
  __shared__ char lds[131072];                // 4 x (A 16KB + B 16KB)
  constexpr int KS = DIN / 32;                // K-steps per phase
  constexpr int S  = 2 * KS;                  // total K-steps (dual-A)
  const int tid = threadIdx.x;
  const int w = tid >> 6, l = tid & 63;
  const int l15 = l & 15, l4 = l >> 4;
  const int wm = w >> 2, wn = w & 3;          // 2 x 4 wave grid

  // bijective XCD swizzle (m204): contiguous tile chunk per XCD; n-tile fastest
  const int nwg  = gridDim.x * gridDim.y;
  const int orig = blockIdx.x + gridDim.x * blockIdx.y;
  const int q = nwg >> 3, r = nwg & 7;
  const int xcd = orig & 7, seq = orig >> 3;
  const int wg = (xcd < r ? xcd * (q + 1) : r * (q + 1) + (xcd - r) * q) + seq;
  const int mt = wg >> 1, nt = wg & 1;        // NT = 2
  const int m0 = mt * 256, n0 = nt * 256;

  f32x4 acc[8][4];
#pragma unroll
  for (int i = 0; i < 8; ++i)
#pragma unroll
    for (int j = 0; j < 4; ++j) acc[i][j] = (f32x4){0.f, 0.f, 0.f, 0.f};

  // staging: wave w stages A m-frags {2w,2w+1} (of 16) and B n-frags {2w,2w+1} (of 16)
  const int arow0 = min(m0 + (2 * w) * 16 + l15, M - 1);
  const int arow1 = min(m0 + (2 * w + 1) * 16 + l15, M - 1);
  const int brow0 = n0 + (2 * w) * 16 + l15;
  const int brow1 = n0 + (2 * w + 1) * 16 + l15;
  const int kl = l4 * 8;                       // lane k-slice
  const u16* pA1r0 = A1  + (size_t)arow0 * DIN + kl;
  const u16* pA1r1 = A1  + (size_t)arow1 * DIN + kl;
  const u16* pA2r0 = A2  + (size_t)arow0 * DIN + kl;
  const u16* pA2r1 = A2  + (size_t)arow1 * DIN + kl;
  const u16* pW1r0 = Wt1 + (size_t)brow0 * DIN + kl;
  const u16* pW1r1 = Wt1 + (size_t)brow1 * DIN + kl;
  const u16* pW2r0 = Wt2 + (size_t)brow0 * DIN + kl;
  const u16* pW2r1 = Wt2 + (size_t)brow1 * DIN + kl;

  auto stage = [&](int s) {                    // 4 global_load_lds per wave
    const int ph = s / KS;
    const int k0 = (s - ph * KS) * 32;
    char* buf = lds + (s & 3) * 32768;
    const u16* a0 = (ph ? pA2r0 : pA1r0) + k0;
    const u16* a1 = (ph ? pA2r1 : pA1r1) + k0;
    const u16* b0 = (ph ? pW2r0 : pW1r0) + k0;
    const u16* b1 = (ph ? pW2r1 : pW1r1) + k0;
    __builtin_amdgcn_global_load_lds(GLOBAL_AS(a0), LDS_AS(buf + (2 * w + 0) * 1024), 16, 0, 0);
    __builtin_amdgcn_global_load_lds(GLOBAL_AS(a1), LDS_AS(buf + (2 * w + 1) * 1024), 16, 0, 0);
    __builtin_amdgcn_global_load_lds(GLOBAL_AS(b0), LDS_AS(buf + 16384 + (2 * w + 0) * 1024), 16, 0, 0);
    __builtin_amdgcn_global_load_lds(GLOBAL_AS(b1), LDS_AS(buf + 16384 + (2 * w + 1) * 1024), 16, 0, 0);
  };

  stage(0);
  stage(1);
  stage(2);
  stage(3);

#pragma unroll
  for (int s = 0; s < S; ++s) {
    // wait for step s's 4 loads; steps s+1..s+3 (12 loads) stay in flight
    const int rem = S - 1 - s;
    if (rem >= 3)      asm volatile("s_waitcnt vmcnt(12)" ::: "memory");
    else if (rem == 2) asm volatile("s_waitcnt vmcnt(8)" ::: "memory");
    else if (rem == 1) asm volatile("s_waitcnt vmcnt(4)" ::: "memory");
    else               asm volatile("s_waitcnt vmcnt(0)" ::: "memory");
    __builtin_amdgcn_s_barrier();
    char* buf = lds + (s & 3) * 32768;
    bf16x8 af[8], bfr[4];
#pragma unroll
    for (int i = 0; i < 8; ++i)
      af[i] = *reinterpret_cast<const bf16x8*>(buf + (wm * 8 + i) * 1024 + l * 16);
#pragma unroll
    for (int j = 0; j < 4; ++j)
      bfr[j] = *reinterpret_cast<const bf16x8*>(buf + 16384 + (wn * 4 + j) * 1024 + l * 16);
#pragma unroll
    for (int i = 0; i < 8; ++i)
#pragma unroll
      for (int j = 0; j < 4; ++j)
        acc[i][j] = __builtin_amdgcn_mfma_f32_16x16x32_bf16(af[i], bfr[j], acc[i][j], 0, 0, 0);
    asm volatile("s_waitcnt lgkmcnt(0)" ::: "memory");   // all reads of buf retired
    __builtin_amdgcn_s_barrier();
    if (s + 4 < S) stage(s + 4);                          // refill this buffer
  }

  // epilogue: C/D mapping col = lane&15, row = (lane>>4)*4 + reg   [m89-verified]
#pragma unroll
  for (int j = 0; j < 4; ++j) {
    const int c = n0 + wn * 64 + j * 16 + l15;
    const float bv = bias[c];
#pragma unroll
    for (int i = 0; i < 8; ++i) {
      const int rowb = m0 + wm * 128 + i * 16 + l4 * 4;
#pragma unroll
      for (int r = 0; r < 4; ++r) {
        const int row = rowb + r;
        if (row < M) {
          float t = acc[i][j][r] + bv;
          if (RELU) t = fmaxf(t, 0.f);
          out[(size_t)row * DOUT + c] = f2bf(t);
        }
      }
    }
  }
}

// ---------------- 128x128 4-wave 3-deep kernel (kept for DOUT=128 / L4) ----------------
template <int DIN, int DOUT, bool RELU>
__global__ __launch_bounds__(256, 3)
void k_gemm(const u16* __restrict__ A1, const u16* __restrict__ A2,
            const u16* __restrict__ Wt1, const u16* __restrict__ Wt2,
            const float* __restrict__ bias, u16* __restrict__ out, int M) {
  __shared__ char lds[49152];                 // 3 x (A 8KB + B 8KB)
  constexpr int KS = DIN / 32;
  constexpr int S  = 2 * KS;
  const int tid = threadIdx.x;
  const int w = tid >> 6, l = tid & 63;
  const int l15 = l & 15, l4 = l >> 4;
  const int wm = w >> 1, wn = w & 1;

  const int nwg  = gridDim.x * gridDim.y;
  const int orig = blockIdx.x + gridDim.x * blockIdx.y;
  const int q = nwg >> 3, r = nwg & 7;
  const int xcd = orig & 7, seq = orig >> 3;
  const int wg = (xcd < r ? xcd * (q + 1) : r * (q + 1) + (xcd - r) * q) + seq;
  constexpr int NT = DOUT / 128;
  const int mt = wg / NT, nt = wg - mt * NT;
  const int m0 = mt * 128, n0 = nt * 128;

  f32x4 acc[4][4];
#pragma unroll
  for (int i = 0; i < 4; ++i)
#pragma unroll
    for (int j = 0; j < 4; ++j) acc[i][j] = (f32x4){0.f, 0.f, 0.f, 0.f};

  const int arow0 = min(m0 + (2 * w) * 16 + l15, M - 1);
  const int arow1 = min(m0 + (2 * w + 1) * 16 + l15, M - 1);
  const int brow0 = n0 + (2 * w) * 16 + l15;
  const int brow1 = n0 + (2 * w + 1) * 16 + l15;
  const int kl = l4 * 8;
  const u16* pA1r0 = A1  + (size_t)arow0 * DIN + kl;
  const u16* pA1r1 = A1  + (size_t)arow1 * DIN + kl;
  const u16* pA2r0 = A2  + (size_t)arow0 * DIN + kl;
  const u16* pA2r1 = A2  + (size_t)arow1 * DIN + kl;
  const u16* pW1r0 = Wt1 + (size_t)brow0 * DIN + kl;
  const u16* pW1r1 = Wt1 + (size_t)brow1 * DIN + kl;
  const u16* pW2r0 = Wt2 + (size_t)brow0 * DIN + kl;
  const u16* pW2r1 = Wt2 + (size_t)brow1 * DIN + kl;

  auto stage = [&](int s) {
    const int ph = s / KS;
    const int k0 = (s - ph * KS) * 32;
    char* buf = lds + (s % 3) * 16384;
    const u16* a0 = (ph ? pA2r0 : pA1r0) + k0;
    const u16* a1 = (ph ? pA2r1 : pA1r1) + k0;
    const u16* b0 = (ph ? pW2r0 : pW1r0) + k0;
    const u16* b1 = (ph ? pW2r1 : pW1r1) + k0;
    __builtin_amdgcn_global_load_lds(GLOBAL_AS(a0), LDS_AS(buf + (2 * w + 0) * 1024), 16, 0, 0);
    __builtin_amdgcn_global_load_lds(GLOBAL_AS(a1), LDS_AS(buf + (2 * w + 1) * 1024), 16, 0, 0);
    __builtin_amdgcn_global_load_lds(GLOBAL_AS(b0), LDS_AS(buf + 8192 + (2 * w + 0) * 1024), 16, 0, 0);
    __builtin_amdgcn_global_load_lds(GLOBAL_AS(b1), LDS_AS(buf + 8192 + (2 * w + 1) * 1024), 16, 0, 0);
  };

  stage(0);
  stage(1);
  stage(2);

#pragma unroll
  for (int s = 0; s < S; ++s) {
    const int rem = S - 1 - s;
    if (rem >= 2)      asm volatile("s_waitcnt vmcnt(8)" ::: "memory");
    else if (rem == 1) asm volatile("s_waitcnt vmcnt(4)" ::: "memory");
    else               asm volatile("s_waitcnt vmcnt(0)" ::: "memory");
    __builtin_amdgcn_s_barrier();
    char* buf = lds + (s % 3) * 16384;
    bf16x8 af[4], bfr[4];
#pragma unroll
    for (int i = 0; i < 4; ++i)
      af[i] = *reinterpret_cast<const bf16x8*>(buf + (wm * 4 + i) * 1024 + l * 16);
#pragma unroll
    for (int j = 0; j < 4; ++j)
      bfr[j] = *reinterpret_cast<const bf16x8*>(buf + 8192 + (wn * 4 + j) * 1024 + l * 16);
#pragma unroll
    for (int i = 0; i < 4; ++i)
#pragma unroll
      for (int j = 0; j < 4; ++j)
        acc[i][j] = __builtin_amdgcn_mfma_f32_16x16x32_bf16(af[i], bfr[j], acc[i][j], 0, 0, 0);
    asm volatile("s_waitcnt lgkmcnt(0)" ::: "memory");
    __builtin_amdgcn_s_barrier();
    if (s + 3 < S) stage(s + 3);
  }

#pragma unroll
  for (int j = 0; j < 4; ++j) {
    const int c = n0 + wn * 64 + j * 16 + l15;
    const float bv = bias[c];
#pragma unroll
    for (int i = 0; i < 4; ++i) {
      const int rowb = m0 + wm * 64 + i * 16 + l4 * 4;
#pragma unroll
      for (int r = 0; r < 4; ++r) {
        const int row = rowb + r;
        if (row < M) {
          float t = acc[i][j][r] + bv;
          if (RELU) t = fmaxf(t, 0.f);
          out[(size_t)row * DOUT + c] = f2bf(t);
        }
      }
    }
  }
}

// ---------------- loss ----------------
__global__ __launch_bounds__(256)
void k_loss1(const u16* __restrict__ dec, const float* __restrict__ attr,
             const int* __restrict__ mask, int NM, float* __restrict__ partials) {
  __shared__ float sm[256];
  float s = 0.f;
  const int total = NM * (IN_DIM / 4);
  for (int idx = blockIdx.x * blockDim.x + threadIdx.x; idx < total; idx += gridDim.x * blockDim.x) {
    const int m = idx >> 5, c = (idx & 31) * 4;
    const int node = mask[m];
    const float4 a = *reinterpret_cast<const float4*>(&attr[(size_t)node * IN_DIM + c]);
    const uint2 d2 = *reinterpret_cast<const uint2*>(&dec[(size_t)node * IN_DIM + c]);
    const float dx = bfu2f(d2.x & 0xffffu) - a.x;
    const float dy = bfu2f(d2.x >> 16)     - a.y;
    const float dz = bfu2f(d2.y & 0xffffu) - a.z;
    const float dw = bfu2f(d2.y >> 16)     - a.w;
    s += dx * dx + dy * dy + dz * dz + dw * dw;
  }
  sm[threadIdx.x] = s;
  __syncthreads();
  for (int off = 128; off > 0; off >>= 1) {
    if (threadIdx.x < off) sm[threadIdx.x] += sm[threadIdx.x + off];
    __syncthreads();
  }
  if (threadIdx.x == 0) partials[blockIdx.x] = sm[0];
}

__global__ __launch_bounds__(256)
void k_loss2(const float* __restrict__ partials, int nb, float* __restrict__ out, float inv) {
  __shared__ float sm[256];
  float s = 0.f;
  for (int i = threadIdx.x; i < nb; i += 256) s += partials[i];
  sm[threadIdx.x] = s;
  __syncthreads();
  for (int off = 128; off > 0; off >>= 1) {
    if (threadIdx.x < off) sm[threadIdx.x] += sm[threadIdx.x + off];
    __syncthreads();
  }
  if (threadIdx.x == 0) out[0] = sm[0] * inv;
}

// ---------------- launch ----------------
extern "C" void kernel_launch(void* const* d_in, const int* in_sizes, int n_in,
                              void* d_out, int out_size, void* d_ws, size_t ws_size,
                              hipStream_t stream) {
  const float* attr  = (const float*)d_in[0];
  const float* token = (const float*)d_in[1];
  const int*   src   = (const int*)d_in[2];
  const int*   dst   = (const int*)d_in[3];
  const int*   mask  = (const int*)d_in[4];
  const float* Wself[4]  = {(const float*)d_in[5], (const float*)d_in[8],
                            (const float*)d_in[11], (const float*)d_in[14]};
  const float* Wneigh[4] = {(const float*)d_in[6], (const float*)d_in[9],
                            (const float*)d_in[12], (const float*)d_in[15]};
  const float* Bias[4]   = {(const float*)d_in[7], (const float*)d_in[10],
                            (const float*)d_in[13], (const float*)d_in[16]};
  const int N  = in_sizes[0] / IN_DIM;
  const int E  = in_sizes[2];
  const int NM = in_sizes[4];

  size_t off = 0;
  auto take = [&](size_t bytes) -> void* {
    void* p = (char*)d_ws + off;
    off += (bytes + 255) & ~(size_t)255;
    return p;
  };
  u16* HA = (u16*)take((size_t)N * HID * sizeof(u16));   // 51.2 MB
  u16* HB = (u16*)take((size_t)N * HID * sizeof(u16));   // 51.2 MB
  const int dims_in[4]  = {IN_DIM, HID, HID, HID};
  const int dims_out[4] = {HID, HID, HID, IN_DIM};
  u16* WtS[4]; u16* WtN[4];
  for (int i = 0; i < 4; ++i) {
    WtS[i] = (u16*)take((size_t)dims_in[i] * dims_out[i] * sizeof(u16));
    WtN[i] = (u16*)take((size_t)dims_in[i] * dims_out[i] * sizeof(u16));
  }
  int* deg    = (int*)take((size_t)N * sizeof(int));
  int* rowptr = (int*)take((size_t)(N + 1) * sizeof(int));
  int* cursor = (int*)take((size_t)N * sizeof(int));
  int* col    = (int*)take((size_t)E * sizeof(int));
  float* partials = (float*)take(512 * sizeof(float));

  // aggregation chunk: prefer one chunk covering N (rounded up to 256 rows for big tiles)
  size_t rem = (ws_size > off + 4096) ? (ws_size - off - 4096) : 0;
  const int cap = (int)(rem / ((size_t)HID * sizeof(u16)));
  const int want = (N + 255) & ~255;
  int chunk = (cap >= want) ? want : (cap & ~255);
  if (chunk < 2048) chunk = 2048;  // last-resort floor
  u16* CH = (u16*)take((size_t)chunk * HID * sizeof(u16));

  // CSR build
  k_zero<<<imin_h((N + 255) / 256, 1024), 256, 0, stream>>>(deg, N);
  const int eb = imin_h((E + 255) / 256, 4096);
  k_hist<<<eb, 256, 0, stream>>>(dst, deg, E);
  k_scan<<<1, 1024, 0, stream>>>(deg, rowptr, cursor, N);
  k_fill<<<eb, 256, 0, stream>>>(src, dst, cursor, col, E);

  // weights: transpose + bf16 once per call
  for (int i = 0; i < 4; ++i) {
    const int tot = dims_in[i] * dims_out[i];
    k_wt<<<imin_h((tot + 255) / 256, 2048), 256, 0, stream>>>(Wself[i],  WtS[i], dims_in[i], dims_out[i]);
    k_wt<<<imin_h((tot + 255) / 256, 2048), 256, 0, stream>>>(Wneigh[i], WtN[i], dims_in[i], dims_out[i]);
  }

  // h0 = bf16(attr) with masked rows = token   (in HA as N x 128)
  const int n4 = N * (IN_DIM / 4);
  k_cvt<<<imin_h((n4 + 255) / 256, 2048), 256, 0, stream>>>((const float4*)attr, (uint2*)HA, n4);
  k_mask<<<imin_h((NM * (IN_DIM / 4) + 255) / 256, 2048), 256, 0, stream>>>(
      (const float4*)token, mask, (uint2*)HA, NM);

  // per-layer chunked: agg chunk -> gemm chunk
  auto run_layer = [&](const u16* hin, u16* hout, int din, int dout, int layer, bool relu) {
    for (int c0 = 0; c0 < N; c0 += chunk) {
      const int mc = imin_h(chunk, N - c0);
      const int ab = (mc + 3) / 4;
      if (din == IN_DIM)
        k_agg<IN_DIM><<<ab, 256, 0, stream>>>(hin, col, rowptr + c0, CH, mc);
      else
        k_agg<HID><<<ab, 256, 0, stream>>>(hin, col, rowptr + c0, CH, mc);
      const u16* a1 = hin + (size_t)c0 * din;
      u16* o = hout + (size_t)c0 * dout;
      if (dout == HID) {
        const int mb = (mc + 255) / 256;
        if (din == IN_DIM && relu)
          k_gemm_big<IN_DIM, true><<<dim3(2, mb), 512, 0, stream>>>(
              a1, CH, WtS[layer], WtN[layer], Bias[layer], o, mc);
        else if (relu)
          k_gemm_big<HID, true><<<dim3(2, mb), 512, 0, stream>>>(
              a1, CH, WtS[layer], WtN[layer], Bias[layer], o, mc);
        else
          k_gemm_big<HID, false><<<dim3(2, mb), 512, 0, stream>>>(
              a1, CH, WtS[layer], WtN[layer], Bias[layer], o, mc);
      } else {
        const int mb = (mc + 127) / 128;
        k_gemm<HID, IN_DIM, false><<<dim3(IN_DIM / 128, mb), 256, 0, stream>>>(
            a1, CH, WtS[layer], WtN[layer], Bias[layer], o, mc);
      }
    }
  };

  run_layer(HA, HB, IN_DIM, HID, 0, true);   // L1: 128->512 relu
  run_layer(HB, HA, HID,    HID, 1, false);  // L2: 512->512
  run_layer(HA, HB, HID,    HID, 2, true);   // L3: 512->512 relu
  run_layer(HB, HA, HID, IN_DIM, 3, false);  // L4: 512->128 (decoded in HA)

  // loss = mean((decoded[mask] - attr[mask])^2)
  k_loss1<<<512, 256, 0, stream>>>(HA, attr, mask, NM, partials);
  k_loss2<<<1, 256, 0, stream>>>(partials, 512, (float*)d_out, 1.0f / ((float)NM * IN_DIM));
}

// Round 10
// 614.372 us; speedup vs baseline: 1.2188x; 1.1378x over previous
//
#include <hip/hip_runtime.h>
#include <cstdint>
#include <cstddef>

#define IN_DIM 128
#define HID    512

typedef unsigned int   uint32;
typedef unsigned short u16;
typedef __attribute__((ext_vector_type(8))) short bf16x8;   // 8 bf16 (4 VGPRs)
typedef __attribute__((ext_vector_type(4))) float f32x4;

static inline int imin_h(int a, int b) { return a < b ? a : b; }

// ---- bf16 helpers (storage-only bf16; accumulation fp32) ----
__device__ __forceinline__ float bfu2f(uint32 u) { return __uint_as_float(u << 16); }
__device__ __forceinline__ u16 f2bf(float f) {
  uint32 x = __float_as_uint(f);
  x += 0x7fffu + ((x >> 16) & 1u);           // round-to-nearest-even
  return (u16)(x >> 16);
}
__device__ __forceinline__ uint32 pack2(float a, float b) {
  return (uint32)f2bf(a) | ((uint32)f2bf(b) << 16);
}

#define GLOBAL_AS(p) ((const __attribute__((address_space(1))) void*)(p))
#define LDS_AS(p)    ((__attribute__((address_space(3))) void*)(p))

// ---------------- misc ----------------
__global__ void k_zero(int* __restrict__ p, int n) {
  for (int i = blockIdx.x * blockDim.x + threadIdx.x; i < n; i += gridDim.x * blockDim.x)
    p[i] = 0;
}

// ---------------- CSR build (by dst) ----------------
__global__ void k_hist(const int* __restrict__ dst, int* __restrict__ deg, int E) {
  for (int e = blockIdx.x * blockDim.x + threadIdx.x; e < E; e += gridDim.x * blockDim.x)
    atomicAdd(&deg[dst[e]], 1);
}

__global__ __launch_bounds__(1024)
void k_scan(const int* __restrict__ deg, int* __restrict__ rowptr, int* __restrict__ cursor, int n) {
  __shared__ int sm[1024];
  __shared__ int carry;
  const int tid = threadIdx.x;
  if (tid == 0) carry = 0;
  __syncthreads();
  for (int base = 0; base < n; base += 1024) {
    const int i = base + tid;
    const int v = (i < n) ? deg[i] : 0;
    sm[tid] = v;
    __syncthreads();
    for (int off = 1; off < 1024; off <<= 1) {
      int t = (tid >= off) ? sm[tid - off] : 0;
      __syncthreads();
      sm[tid] += t;
      __syncthreads();
    }
    const int excl = sm[tid] - v;
    if (i < n) { const int r = carry + excl; rowptr[i] = r; cursor[i] = r; }
    __syncthreads();
    if (tid == 1023) carry += sm[1023];
    __syncthreads();
  }
  if (tid == 0) rowptr[n] = carry;
}

__global__ void k_fill(const int* __restrict__ src, const int* __restrict__ dst,
                       int* __restrict__ cursor, int* __restrict__ col, int E) {
  for (int e = blockIdx.x * blockDim.x + threadIdx.x; e < E; e += gridDim.x * blockDim.x) {
    const int p = atomicAdd(&cursor[dst[e]], 1);
    col[p] = src[e];
  }
}

// ---------------- h0 = bf16(attr); masked rows = token ----------------
__global__ void k_cvt(const float4* __restrict__ in, uint2* __restrict__ out, int n4) {
  for (int i = blockIdx.x * blockDim.x + threadIdx.x; i < n4; i += gridDim.x * blockDim.x) {
    const float4 v = in[i];
    out[i] = make_uint2(pack2(v.x, v.y), pack2(v.z, v.w));
  }
}

__global__ void k_mask(const float4* __restrict__ token, const int* __restrict__ mask,
                       uint2* __restrict__ h0, int NM) {
  const int total = NM * (IN_DIM / 4);
  for (int i = blockIdx.x * blockDim.x + threadIdx.x; i < total; i += gridDim.x * blockDim.x) {
    const int m = i >> 5;
    const int c = i & 31;
    const float4 t = token[c];
    h0[(size_t)mask[m] * (IN_DIM / 4) + c] = make_uint2(pack2(t.x, t.y), pack2(t.z, t.w));
  }
}

// ------- weight transpose + convert + FRAGMENT-PACK ----------------------------------
// Packed layout: frag f = (n>>4)*(K/32) + (k>>5), each frag = 512 u16 (1 KiB) in exact
// MFMA lane order: u16 idx = f*512 + ((k>>3)&3)*128 + (n&15)*8 + (k&7).
// GEMM B staging then loads one frag = one fully-contiguous 1 KiB global_load_lds.
__global__ void k_wt(const float* __restrict__ W, u16* __restrict__ Wt, int K, int Nn) {
  const int total = K * Nn;
  for (int t = blockIdx.x * blockDim.x + threadIdx.x; t < total; t += gridDim.x * blockDim.x) {
    const int n = t / K, k = t - n * K;
    const size_t idx = ((size_t)(n >> 4) * (K >> 5) + (k >> 5)) * 512 +
                       ((k >> 3) & 3) * 128 + ((n & 15) << 3) + (k & 7);
    Wt[idx] = f2bf(W[(size_t)k * Nn + n]);
  }
}

// -------- mean aggregation over in-neighbors (CSR gather, 1 wave/node, 2-deep) --------
// REMAP: node id = nodes[w] (compact output row w) — used for the mask-restricted L4.
template <int D, bool REMAP>
__global__ __launch_bounds__(256)
void k_agg(const u16* __restrict__ h, const int* __restrict__ col,
           const int* __restrict__ rowptr, const int* __restrict__ nodes,
           u16* __restrict__ out, int n) {
  constexpr int V = D / 64;  // bf16 per lane: 8 (D=512) or 2 (D=128)
  const int w = blockIdx.x * (blockDim.x >> 6) + (threadIdx.x >> 6);
  if (w >= n) return;
  const int node = REMAP ? nodes[w] : w;
  const int lane = threadIdx.x & 63;
  const int beg = rowptr[node], end = rowptr[node + 1];
  const size_t loff = (size_t)lane * V;
  float acc[V];
#pragma unroll
  for (int j = 0; j < V; ++j) acc[j] = 0.f;
  if constexpr (V == 8) {
    uint4 cur;
    if (beg < end) cur = *reinterpret_cast<const uint4*>(h + (size_t)col[beg] * D + loff);
    for (int e = beg; e < end; ++e) {
      uint4 nxt = cur;
      if (e + 1 < end)
        nxt = *reinterpret_cast<const uint4*>(h + (size_t)col[e + 1] * D + loff);
      acc[0] += bfu2f(cur.x & 0xffffu); acc[1] += bfu2f(cur.x >> 16);
      acc[2] += bfu2f(cur.y & 0xffffu); acc[3] += bfu2f(cur.y >> 16);
      acc[4] += bfu2f(cur.z & 0xffffu); acc[5] += bfu2f(cur.z >> 16);
      acc[6] += bfu2f(cur.w & 0xffffu); acc[7] += bfu2f(cur.w >> 16);
      cur = nxt;
    }
  } else {
    uint32 cur = 0;
    if (beg < end) cur = *reinterpret_cast<const uint32*>(h + (size_t)col[beg] * D + loff);
    for (int e = beg; e < end; ++e) {
      uint32 nxt = cur;
      if (e + 1 < end)
        nxt = *reinterpret_cast<const uint32*>(h + (size_t)col[e + 1] * D + loff);
      acc[0] += bfu2f(cur & 0xffffu); acc[1] += bfu2f(cur >> 16);
      cur = nxt;
    }
  }
  const float inv = 1.0f / fmaxf((float)(end - beg), 1.0f);
  u16* o = out + (size_t)w * D + loff;
  if constexpr (V == 8) {
    uint4 u;
    u.x = pack2(acc[0] * inv, acc[1] * inv);
    u.y = pack2(acc[2] * inv, acc[3] * inv);
    u.z = pack2(acc[4] * inv, acc[5] * inv);
    u.w = pack2(acc[6] * inv, acc[7] * inv);
    *reinterpret_cast<uint4*>(o) = u;
  } else {
    *reinterpret_cast<uint32*>(o) = pack2(acc[0] * inv, acc[1] * inv);
  }
}

// ======== dual-A bf16 MFMA GEMM, 256x256 tile, 8 waves, 4-deep counted-vmcnt pipeline ===
// out = bf16(A1@W1 + A2@W2 + b), opt ReLU.  DOUT = 512 fixed (NT = 2 n-tiles).
// A row-major (scattered 16-row staging); Wt FRAGMENT-PACKED (contiguous 1KiB staging).
template <int DIN, bool RELU>
__global__ __launch_bounds__(512, 2)
void k_gemm_big(const u16* __restrict__ A1, const u16* __restrict__ A2,
                const u16* __restrict__ Wt1, const u16* __restrict__ Wt2,
                const float* __restrict__ bias, u16* __restrict__ out, int M) {
  constexpr int DOUT = HID;
  __shared__ char lds[131072];                // 4 x (A 16KB + B 16KB)
  constexpr int KS = DIN / 32;                // K-steps per phase (1 k-frag per step)
  constexpr int S  = 2 * KS;                  // total K-steps (dual-A)
  const int tid = threadIdx.x;
  const int w = tid >> 6, l = tid & 63;
  const int l15 = l & 15, l4 = l >> 4;
  const int wm = w >> 2, wn = w & 3;          // 2 x 4 wave grid

  const int nwg  = gridDim.x * gridDim.y;
  const int orig = blockIdx.x + gridDim.x * blockIdx.y;
  const int q = nwg >> 3, r = nwg & 7;
  const int xcd = orig & 7, seq = orig >> 3;
  const int wg = (xcd < r ? xcd * (q + 1) : r * (q + 1) + (xcd - r) * q) + seq;
  const int mt = wg >> 1, nt = wg & 1;        // NT = 2
  const int m0 = mt * 256, n0 = nt * 256;

  f32x4 acc[8][4];
#pragma unroll
  for (int i = 0; i < 8; ++i)
#pragma unroll
    for (int j = 0; j < 4; ++j) acc[i][j] = (f32x4){0.f, 0.f, 0.f, 0.f};

  // A staging (row-major): wave w stages m-frags {2w,2w+1}
  const int arow0 = min(m0 + (2 * w) * 16 + l15, M - 1);
  const int arow1 = min(m0 + (2 * w + 1) * 16 + l15, M - 1);
  const int kl = l4 * 8;
  const u16* pA1r0 = A1 + (size_t)arow0 * DIN + kl;
  const u16* pA1r1 = A1 + (size_t)arow1 * DIN + kl;
  const u16* pA2r0 = A2 + (size_t)arow0 * DIN + kl;
  const u16* pA2r1 = A2 + (size_t)arow1 * DIN + kl;
  // B staging (fragment-packed): wave w stages n-frags {2w,2w+1}; contiguous 1KiB each
  const u16* bb1 = Wt1 + ((size_t)(n0 >> 4) + 2 * w) * KS * 512 + (size_t)l * 8;
  const u16* bb2 = Wt2 + ((size_t)(n0 >> 4) + 2 * w) * KS * 512 + (size_t)l * 8;

  auto stage = [&](int s) {                    // 4 global_load_lds per wave
    const int ph = s / KS;
    const int kf = s - ph * KS;
    char* buf = lds + (s & 3) * 32768;
    const u16* a0 = (ph ? pA2r0 : pA1r0) + kf * 32;
    const u16* a1 = (ph ? pA2r1 : pA1r1) + kf * 32;
    const u16* b0 = (ph ? bb2 : bb1) + kf * 512;
    const u16* b1 = b0 + KS * 512;             // next n-frag
    __builtin_amdgcn_global_load_lds(GLOBAL_AS(a0), LDS_AS(buf + (2 * w + 0) * 1024), 16, 0, 0);
    __builtin_amdgcn_global_load_lds(GLOBAL_AS(a1), LDS_AS(buf + (2 * w + 1) * 1024), 16, 0, 0);
    __builtin_amdgcn_global_load_lds(GLOBAL_AS(b0), LDS_AS(buf + 16384 + (2 * w + 0) * 1024), 16, 0, 0);
    __builtin_amdgcn_global_load_lds(GLOBAL_AS(b1), LDS_AS(buf + 16384 + (2 * w + 1) * 1024), 16, 0, 0);
  };

  stage(0);
  stage(1);
  stage(2);
  stage(3);

#pragma unroll
  for (int s = 0; s < S; ++s) {
    const int rem = S - 1 - s;
    if (rem >= 3)      asm volatile("s_waitcnt vmcnt(12)" ::: "memory");
    else if (rem == 2) asm volatile("s_waitcnt vmcnt(8)" ::: "memory");
    else if (rem == 1) asm volatile("s_waitcnt vmcnt(4)" ::: "memory");
    else               asm volatile("s_waitcnt vmcnt(0)" ::: "memory");
    __builtin_amdgcn_s_barrier();
    char* buf = lds + (s & 3) * 32768;
    bf16x8 af[8], bfr[4];
#pragma unroll
    for (int i = 0; i < 8; ++i)
      af[i] = *reinterpret_cast<const bf16x8*>(buf + (wm * 8 + i) * 1024 + l * 16);
#pragma unroll
    for (int j = 0; j < 4; ++j)
      bfr[j] = *reinterpret_cast<const bf16x8*>(buf + 16384 + (wn * 4 + j) * 1024 + l * 16);
#pragma unroll
    for (int i = 0; i < 8; ++i)
#pragma unroll
      for (int j = 0; j < 4; ++j)
        acc[i][j] = __builtin_amdgcn_mfma_f32_16x16x32_bf16(af[i], bfr[j], acc[i][j], 0, 0, 0);
    asm volatile("s_waitcnt lgkmcnt(0)" ::: "memory");
    __builtin_amdgcn_s_barrier();
    if (s + 4 < S) stage(s + 4);
  }

  // epilogue: C/D mapping col = lane&15, row = (lane>>4)*4 + reg   [m89-verified]
#pragma unroll
  for (int j = 0; j < 4; ++j) {
    const int c = n0 + wn * 64 + j * 16 + l15;
    const float bv = bias[c];
#pragma unroll
    for (int i = 0; i < 8; ++i) {
      const int rowb = m0 + wm * 128 + i * 16 + l4 * 4;
#pragma unroll
      for (int r = 0; r < 4; ++r) {
        const int row = rowb + r;
        if (row < M) {
          float t = acc[i][j][r] + bv;
          if (RELU) t = fmaxf(t, 0.f);
          out[(size_t)row * DOUT + c] = f2bf(t);
        }
      }
    }
  }
}

// -------- 128x128 4-wave 3-deep kernel (DOUT=128, optional A1-row remap — L4) ----------
template <int DIN, int DOUT, bool RELU, bool REMAP>
__global__ __launch_bounds__(256, 3)
void k_gemm(const u16* __restrict__ A1, const u16* __restrict__ A2,
            const u16* __restrict__ Wt1, const u16* __restrict__ Wt2,
            const float* __restrict__ bias, u16* __restrict__ out, int M,
            const int* __restrict__ remap) {
  __shared__ char lds[49152];                 // 3 x (A 8KB + B 8KB)
  constexpr int KS = DIN / 32;
  constexpr int S  = 2 * KS;
  const int tid = threadIdx.x;
  const int w = tid >> 6, l = tid & 63;
  const int l15 = l & 15, l4 = l >> 4;
  const int wm = w >> 1, wn = w & 1;

  const int nwg  = gridDim.x * gridDim.y;
  const int orig = blockIdx.x + gridDim.x * blockIdx.y;
  const int q = nwg >> 3, r = nwg & 7;
  const int xcd = orig & 7, seq = orig >> 3;
  const int wg = (xcd < r ? xcd * (q + 1) : r * (q + 1) + (xcd - r) * q) + seq;
  constexpr int NT = DOUT / 128;
  const int mt = wg / NT, nt = wg - mt * NT;
  const int m0 = mt * 128, n0 = nt * 128;

  f32x4 acc[4][4];
#pragma unroll
  for (int i = 0; i < 4; ++i)
#pragma unroll
    for (int j = 0; j < 4; ++j) acc[i][j] = (f32x4){0.f, 0.f, 0.f, 0.f};

  const int am0 = min(m0 + (2 * w) * 16 + l15, M - 1);        // compact row (A2)
  const int am1 = min(m0 + (2 * w + 1) * 16 + l15, M - 1);
  const int ar0 = REMAP ? remap[am0] : am0;                   // global row (A1)
  const int ar1 = REMAP ? remap[am1] : am1;
  const int kl = l4 * 8;
  const u16* pA1r0 = A1 + (size_t)ar0 * DIN + kl;
  const u16* pA1r1 = A1 + (size_t)ar1 * DIN + kl;
  const u16* pA2r0 = A2 + (size_t)am0 * DIN + kl;
  const u16* pA2r1 = A2 + (size_t)am1 * DIN + kl;
  const u16* bb1 = Wt1 + ((size_t)(n0 >> 4) + 2 * w) * KS * 512 + (size_t)l * 8;
  const u16* bb2 = Wt2 + ((size_t)(n0 >> 4) + 2 * w) * KS * 512 + (size_t)l * 8;

  auto stage = [&](int s) {
    const int ph = s / KS;
    const int kf = s - ph * KS;
    char* buf = lds + (s % 3) * 16384;
    const u16* a0 = (ph ? pA2r0 : pA1r0) + kf * 32;
    const u16* a1 = (ph ? pA2r1 : pA1r1) + kf * 32;
    const u16* b0 = (ph ? bb2 : bb1) + kf * 512;
    const u16* b1 = b0 + KS * 512;
    __builtin_amdgcn_global_load_lds(GLOBAL_AS(a0), LDS_AS(buf + (2 * w + 0) * 1024), 16, 0, 0);
    __builtin_amdgcn_global_load_lds(GLOBAL_AS(a1), LDS_AS(buf + (2 * w + 1) * 1024), 16, 0, 0);
    __builtin_amdgcn_global_load_lds(GLOBAL_AS(b0), LDS_AS(buf + 8192 + (2 * w + 0) * 1024), 16, 0, 0);
    __builtin_amdgcn_global_load_lds(GLOBAL_AS(b1), LDS_AS(buf + 8192 + (2 * w + 1) * 1024), 16, 0, 0);
  };

  stage(0);
  stage(1);
  stage(2);

#pragma unroll
  for (int s = 0; s < S; ++s) {
    const int rem = S - 1 - s;
    if (rem >= 2)      asm volatile("s_waitcnt vmcnt(8)" ::: "memory");
    else if (rem == 1) asm volatile("s_waitcnt vmcnt(4)" ::: "memory");
    else               asm volatile("s_waitcnt vmcnt(0)" ::: "memory");
    __builtin_amdgcn_s_barrier();
    char* buf = lds + (s % 3) * 16384;
    bf16x8 af[4], bfr[4];
#pragma unroll
    for (int i = 0; i < 4; ++i)
      af[i] = *reinterpret_cast<const bf16x8*>(buf + (wm * 4 + i) * 1024 + l * 16);
#pragma unroll
    for (int j = 0; j < 4; ++j)
      bfr[j] = *reinterpret_cast<const bf16x8*>(buf + 8192 + (wn * 4 + j) * 1024 + l * 16);
#pragma unroll
    for (int i = 0; i < 4; ++i)
#pragma unroll
      for (int j = 0; j < 4; ++j)
        acc[i][j] = __builtin_amdgcn_mfma_f32_16x16x32_bf16(af[i], bfr[j], acc[i][j], 0, 0, 0);
    asm volatile("s_waitcnt lgkmcnt(0)" ::: "memory");
    __builtin_amdgcn_s_barrier();
    if (s + 3 < S) stage(s + 3);
  }

#pragma unroll
  for (int j = 0; j < 4; ++j) {
    const int c = n0 + wn * 64 + j * 16 + l15;
    const float bv = bias[c];
#pragma unroll
    for (int i = 0; i < 4; ++i) {
      const int rowb = m0 + wm * 64 + i * 16 + l4 * 4;
#pragma unroll
      for (int r = 0; r < 4; ++r) {
        const int row = rowb + r;
        if (row < M) {
          float t = acc[i][j][r] + bv;
          if (RELU) t = fmaxf(t, 0.f);
          out[(size_t)row * DOUT + c] = f2bf(t);
        }
      }
    }
  }
}

// ---------------- loss (dec is COMPACT: NM x 128, slot m <-> node mask[m]) -------------
__global__ __launch_bounds__(256)
void k_loss1(const u16* __restrict__ dec, const float* __restrict__ attr,
             const int* __restrict__ mask, int NM, float* __restrict__ partials) {
  __shared__ float sm[256];
  float s = 0.f;
  const int total = NM * (IN_DIM / 4);
  for (int idx = blockIdx.x * blockDim.x + threadIdx.x; idx < total; idx += gridDim.x * blockDim.x) {
    const int m = idx >> 5, c = (idx & 31) * 4;
    const int node = mask[m];
    const float4 a = *reinterpret_cast<const float4*>(&attr[(size_t)node * IN_DIM + c]);
    const uint2 d2 = *reinterpret_cast<const uint2*>(&dec[(size_t)m * IN_DIM + c]);
    const float dx = bfu2f(d2.x & 0xffffu) - a.x;
    const float dy = bfu2f(d2.x >> 16)     - a.y;
    const float dz = bfu2f(d2.y & 0xffffu) - a.z;
    const float dw = bfu2f(d2.y >> 16)     - a.w;
    s += dx * dx + dy * dy + dz * dz + dw * dw;
  }
  sm[threadIdx.x] = s;
  __syncthreads();
  for (int off = 128; off > 0; off >>= 1) {
    if (threadIdx.x < off) sm[threadIdx.x] += sm[threadIdx.x + off];
    __syncthreads();
  }
  if (threadIdx.x == 0) partials[blockIdx.x] = sm[0];
}

__global__ __launch_bounds__(256)
void k_loss2(const float* __restrict__ partials, int nb, float* __restrict__ out, float inv) {
  __shared__ float sm[256];
  float s = 0.f;
  for (int i = threadIdx.x; i < nb; i += 256) s += partials[i];
  sm[threadIdx.x] = s;
  __syncthreads();
  for (int off = 128; off > 0; off >>= 1) {
    if (threadIdx.x < off) sm[threadIdx.x] += sm[threadIdx.x + off];
    __syncthreads();
  }
  if (threadIdx.x == 0) out[0] = sm[0] * inv;
}

// ---------------- launch ----------------
extern "C" void kernel_launch(void* const* d_in, const int* in_sizes, int n_in,
                              void* d_out, int out_size, void* d_ws, size_t ws_size,
                              hipStream_t stream) {
  const float* attr  = (const float*)d_in[0];
  const float* token = (const float*)d_in[1];
  const int*   src   = (const int*)d_in[2];
  const int*   dst   = (const int*)d_in[3];
  const int*   mask  = (const int*)d_in[4];
  const float* Wself[4]  = {(const float*)d_in[5], (const float*)d_in[8],
                            (const float*)d_in[11], (const float*)d_in[14]};
  const float* Wneigh[4] = {(const float*)d_in[6], (const float*)d_in[9],
                            (const float*)d_in[12], (const float*)d_in[15]};
  const float* Bias[4]   = {(const float*)d_in[7], (const float*)d_in[10],
                            (const float*)d_in[13], (const float*)d_in[16]};
  const int N  = in_sizes[0] / IN_DIM;
  const int E  = in_sizes[2];
  const int NM = in_sizes[4];

  size_t off = 0;
  auto take = [&](size_t bytes) -> void* {
    void* p = (char*)d_ws + off;
    off += (bytes + 255) & ~(size_t)255;
    return p;
  };
  u16* HA = (u16*)take((size_t)N * HID * sizeof(u16));   // 51.2 MB
  u16* HB = (u16*)take((size_t)N * HID * sizeof(u16));   // 51.2 MB
  const int dims_in[4]  = {IN_DIM, HID, HID, HID};
  const int dims_out[4] = {HID, HID, HID, IN_DIM};
  u16* WtS[4]; u16* WtN[4];
  for (int i = 0; i < 4; ++i) {
    WtS[i] = (u16*)take((size_t)dims_in[i] * dims_out[i] * sizeof(u16));
    WtN[i] = (u16*)take((size_t)dims_in[i] * dims_out[i] * sizeof(u16));
  }
  int* deg    = (int*)take((size_t)N * sizeof(int));
  int* rowptr = (int*)take((size_t)(N + 1) * sizeof(int));
  int* cursor = (int*)take((size_t)N * sizeof(int));
  int* col    = (int*)take((size_t)E * sizeof(int));
  float* partials = (float*)take(512 * sizeof(float));

  // agg chunk: one chunk covering N (rounded to 256)
  size_t rem = (ws_size > off + 4096) ? (ws_size - off - 4096) : 0;
  const int cap = (int)(rem / ((size_t)HID * sizeof(u16)));
  const int want = (N + 255) & ~255;
  int chunk = (cap >= want) ? want : (cap & ~255);
  if (chunk < 2048) chunk = 2048;
  u16* CH = (u16*)take((size_t)chunk * HID * sizeof(u16));
  u16* DEC = HA;                               // decoded compact (NM x 128) reuses HA (dead after L3)

  // CSR build
  k_zero<<<imin_h((N + 255) / 256, 1024), 256, 0, stream>>>(deg, N);
  const int eb = imin_h((E + 255) / 256, 4096);
  k_hist<<<eb, 256, 0, stream>>>(dst, deg, E);
  k_scan<<<1, 1024, 0, stream>>>(deg, rowptr, cursor, N);
  k_fill<<<eb, 256, 0, stream>>>(src, dst, cursor, col, E);

  // weights: transpose + bf16 + fragment-pack once per call
  for (int i = 0; i < 4; ++i) {
    const int tot = dims_in[i] * dims_out[i];
    k_wt<<<imin_h((tot + 255) / 256, 2048), 256, 0, stream>>>(Wself[i],  WtS[i], dims_in[i], dims_out[i]);
    k_wt<<<imin_h((tot + 255) / 256, 2048), 256, 0, stream>>>(Wneigh[i], WtN[i], dims_in[i], dims_out[i]);
  }

  // h0 = bf16(attr) with masked rows = token   (in HA as N x 128)
  const int n4 = N * (IN_DIM / 4);
  k_cvt<<<imin_h((n4 + 255) / 256, 2048), 256, 0, stream>>>((const float4*)attr, (uint2*)HA, n4);
  k_mask<<<imin_h((NM * (IN_DIM / 4) + 255) / 256, 2048), 256, 0, stream>>>(
      (const float4*)token, mask, (uint2*)HA, NM);

  // L1..L3 (full N, DOUT=512): agg chunk -> big gemm
  auto run_layer = [&](const u16* hin, u16* hout, int din, int layer, bool relu) {
    for (int c0 = 0; c0 < N; c0 += chunk) {
      const int mc = imin_h(chunk, N - c0);
      const int ab = (mc + 3) / 4;
      if (din == IN_DIM)
        k_agg<IN_DIM, false><<<ab, 256, 0, stream>>>(hin, col, rowptr + c0, nullptr, CH, mc);
      else
        k_agg<HID, false><<<ab, 256, 0, stream>>>(hin, col, rowptr + c0, nullptr, CH, mc);
      const u16* a1 = hin + (size_t)c0 * din;
      u16* o = hout + (size_t)c0 * HID;
      const int mb = (mc + 255) / 256;
      if (din == IN_DIM && relu)
        k_gemm_big<IN_DIM, true><<<dim3(2, mb), 512, 0, stream>>>(
            a1, CH, WtS[layer], WtN[layer], Bias[layer], o, mc);
      else if (relu)
        k_gemm_big<HID, true><<<dim3(2, mb), 512, 0, stream>>>(
            a1, CH, WtS[layer], WtN[layer], Bias[layer], o, mc);
      else
        k_gemm_big<HID, false><<<dim3(2, mb), 512, 0, stream>>>(
            a1, CH, WtS[layer], WtN[layer], Bias[layer], o, mc);
    }
  };

  run_layer(HA, HB, IN_DIM, 0, true);   // L1: 128->512 relu   (HA h0 -> HB h1)
  run_layer(HB, HA, HID,    1, false);  // L2: 512->512        (HB h1 -> HA h2)
  run_layer(HA, HB, HID,    2, true);   // L3: 512->512 relu   (HA h2 -> HB h3)

  // L4 mask-restricted: decoded only at mask nodes (compact NM rows)
  k_agg<HID, true><<<(NM + 3) / 4, 256, 0, stream>>>(HB, col, rowptr, mask, CH, NM);
  k_gemm<HID, IN_DIM, false, true><<<dim3(1, (NM + 127) / 128), 256, 0, stream>>>(
      HB, CH, WtS[3], WtN[3], Bias[3], DEC, NM, mask);

  // loss = mean((decoded[mask] - attr[mask])^2)
  k_loss1<<<512, 256, 0, stream>>>(DEC, attr, mask, NM, partials);
  k_loss2<<<1, 256, 0, stream>>>(partials, 512, (float*)d_out, 1.0f / ((float)NM * IN_DIM));
}

// Round 11
// 535.722 us; speedup vs baseline: 1.3978x; 1.1468x over previous
//
#include <hip/hip_runtime.h>
#include <cstdint>
#include <cstddef>

#define IN_DIM 128
#define HID    512

typedef unsigned int   uint32;
typedef unsigned short u16;
typedef __attribute__((ext_vector_type(8))) short bf16x8;   // 8 bf16 (4 VGPRs)
typedef __attribute__((ext_vector_type(4))) float f32x4;

static inline int imin_h(int a, int b) { return a < b ? a : b; }

// ---- bf16 helpers (storage-only bf16; accumulation fp32) ----
__device__ __forceinline__ float bfu2f(uint32 u) { return __uint_as_float(u << 16); }
__device__ __forceinline__ u16 f2bf(float f) {
  uint32 x = __float_as_uint(f);
  x += 0x7fffu + ((x >> 16) & 1u);           // round-to-nearest-even
  return (u16)(x >> 16);
}
__device__ __forceinline__ uint32 pack2(float a, float b) {
  return (uint32)f2bf(a) | ((uint32)f2bf(b) << 16);
}

#define GLOBAL_AS(p) ((const __attribute__((address_space(1))) void*)(p))
#define LDS_AS(p)    ((__attribute__((address_space(3))) void*)(p))

// ---------------- misc ----------------
__global__ void k_zero(int* __restrict__ p, int n) {
  for (int i = blockIdx.x * blockDim.x + threadIdx.x; i < n; i += gridDim.x * blockDim.x)
    p[i] = 0;
}

// ---------------- CSR build (by dst) ----------------
__global__ void k_hist(const int* __restrict__ dst, int* __restrict__ deg, int E) {
  for (int e = blockIdx.x * blockDim.x + threadIdx.x; e < E; e += gridDim.x * blockDim.x)
    atomicAdd(&deg[dst[e]], 1);
}

__global__ __launch_bounds__(1024)
void k_scan(const int* __restrict__ deg, int* __restrict__ rowptr, int* __restrict__ cursor, int n) {
  __shared__ int sm[1024];
  __shared__ int carry;
  const int tid = threadIdx.x;
  if (tid == 0) carry = 0;
  __syncthreads();
  for (int base = 0; base < n; base += 1024) {
    const int i = base + tid;
    const int v = (i < n) ? deg[i] : 0;
    sm[tid] = v;
    __syncthreads();
    for (int off = 1; off < 1024; off <<= 1) {
      int t = (tid >= off) ? sm[tid - off] : 0;
      __syncthreads();
      sm[tid] += t;
      __syncthreads();
    }
    const int excl = sm[tid] - v;
    if (i < n) { const int r = carry + excl; rowptr[i] = r; cursor[i] = r; }
    __syncthreads();
    if (tid == 1023) carry += sm[1023];
    __syncthreads();
  }
  if (tid == 0) rowptr[n] = carry;
}

__global__ void k_fill(const int* __restrict__ src, const int* __restrict__ dst,
                       int* __restrict__ cursor, int* __restrict__ col, int E) {
  for (int e = blockIdx.x * blockDim.x + threadIdx.x; e < E; e += gridDim.x * blockDim.x) {
    const int p = atomicAdd(&cursor[dst[e]], 1);
    col[p] = src[e];
  }
}

// ---------------- h0 = bf16(attr); masked rows = token ----------------
__global__ void k_cvt(const float4* __restrict__ in, uint2* __restrict__ out, int n4) {
  for (int i = blockIdx.x * blockDim.x + threadIdx.x; i < n4; i += gridDim.x * blockDim.x) {
    const float4 v = in[i];
    out[i] = make_uint2(pack2(v.x, v.y), pack2(v.z, v.w));
  }
}

__global__ void k_mask(const float4* __restrict__ token, const int* __restrict__ mask,
                       uint2* __restrict__ h0, int NM) {
  const int total = NM * (IN_DIM / 4);
  for (int i = blockIdx.x * blockDim.x + threadIdx.x; i < total; i += gridDim.x * blockDim.x) {
    const int m = i >> 5;
    const int c = i & 31;
    const float4 t = token[c];
    h0[(size_t)mask[m] * (IN_DIM / 4) + c] = make_uint2(pack2(t.x, t.y), pack2(t.z, t.w));
  }
}

// ------- weight transpose + convert + FRAGMENT-PACK ----------------------------------
// frag f = (n>>4)*(K/32) + (k>>5); u16 idx = f*512 + ((k>>3)&3)*128 + (n&15)*8 + (k&7).
__global__ void k_wt(const float* __restrict__ W, u16* __restrict__ Wt, int K, int Nn) {
  const int total = K * Nn;
  for (int t = blockIdx.x * blockDim.x + threadIdx.x; t < total; t += gridDim.x * blockDim.x) {
    const int n = t / K, k = t - n * K;
    const size_t idx = ((size_t)(n >> 4) * (K >> 5) + (k >> 5)) * 512 +
                       ((k >> 3) & 3) * 128 + ((n & 15) << 3) + (k & 7);
    Wt[idx] = f2bf(W[(size_t)k * Nn + n]);
  }
}

// -------- mean aggregation over in-neighbors (CSR gather, 1 wave/node, 2-deep) --------
template <int D, bool REMAP>
__global__ __launch_bounds__(256)
void k_agg(const u16* __restrict__ h, const int* __restrict__ col,
           const int* __restrict__ rowptr, const int* __restrict__ nodes,
           u16* __restrict__ out, int n) {
  constexpr int V = D / 64;
  const int w = blockIdx.x * (blockDim.x >> 6) + (threadIdx.x >> 6);
  if (w >= n) return;
  const int node = REMAP ? nodes[w] : w;
  const int lane = threadIdx.x & 63;
  const int beg = rowptr[node], end = rowptr[node + 1];
  const size_t loff = (size_t)lane * V;
  float acc[V];
#pragma unroll
  for (int j = 0; j < V; ++j) acc[j] = 0.f;
  if constexpr (V == 8) {
    uint4 cur;
    if (beg < end) cur = *reinterpret_cast<const uint4*>(h + (size_t)col[beg] * D + loff);
    for (int e = beg; e < end; ++e) {
      uint4 nxt = cur;
      if (e + 1 < end)
        nxt = *reinterpret_cast<const uint4*>(h + (size_t)col[e + 1] * D + loff);
      acc[0] += bfu2f(cur.x & 0xffffu); acc[1] += bfu2f(cur.x >> 16);
      acc[2] += bfu2f(cur.y & 0xffffu); acc[3] += bfu2f(cur.y >> 16);
      acc[4] += bfu2f(cur.z & 0xffffu); acc[5] += bfu2f(cur.z >> 16);
      acc[6] += bfu2f(cur.w & 0xffffu); acc[7] += bfu2f(cur.w >> 16);
      cur = nxt;
    }
  } else {
    uint32 cur = 0;
    if (beg < end) cur = *reinterpret_cast<const uint32*>(h + (size_t)col[beg] * D + loff);
    for (int e = beg; e < end; ++e) {
      uint32 nxt = cur;
      if (e + 1 < end)
        nxt = *reinterpret_cast<const uint32*>(h + (size_t)col[e + 1] * D + loff);
      acc[0] += bfu2f(cur & 0xffffu); acc[1] += bfu2f(cur >> 16);
      cur = nxt;
    }
  }
  const float inv = 1.0f / fmaxf((float)(end - beg), 1.0f);
  u16* o = out + (size_t)w * D + loff;
  if constexpr (V == 8) {
    uint4 u;
    u.x = pack2(acc[0] * inv, acc[1] * inv);
    u.y = pack2(acc[2] * inv, acc[3] * inv);
    u.z = pack2(acc[4] * inv, acc[5] * inv);
    u.w = pack2(acc[6] * inv, acc[7] * inv);
    *reinterpret_cast<uint4*>(o) = u;
  } else {
    *reinterpret_cast<uint32*>(o) = pack2(acc[0] * inv, acc[1] * inv);
  }
}

// ======== dual-A bf16 MFMA GEMM: 128x256 tile, 8 waves of 64x64, 2 blocks/CU ===========
// out = bf16(A1@W1 + A2@W2 + b), opt ReLU.  DOUT = 512 (NT = 2 n-tiles of 256).
// acc = 64 regs/wave -> <=128 unified regs -> 4 waves/SIMD -> 2 co-resident blocks/CU
// (independent barrier groups = real TLP). 3 rotating 24KB LDS buffers (72KB).
// Per step: A 8 frags + B 16 frags = 3 loads/wave; prefetch 2 ahead, vmcnt(6/3/0).
// Epilogue: C -> LDS (bf16, 72-u16 padded rows) -> 16B/lane coalesced global stores.
template <int DIN, bool RELU>
__global__ __launch_bounds__(512, 4)
void k_gemm_big(const u16* __restrict__ A1, const u16* __restrict__ A2,
                const u16* __restrict__ Wt1, const u16* __restrict__ Wt2,
                const float* __restrict__ bias, u16* __restrict__ out, int M) {
  constexpr int DOUT = HID;
  __shared__ char lds[73728];                 // 3 x (A 8KB + B 16KB); epilogue: 8 x 9216B
  constexpr int KS = DIN / 32;                // k-frags per phase
  constexpr int S  = 2 * KS;                  // total K-steps (dual-A)
  const int tid = threadIdx.x;
  const int w = tid >> 6, l = tid & 63;
  const int l15 = l & 15, l4 = l >> 4;
  const int wm = w >> 2, wn = w & 3;          // 2 x 4 wave grid, wave tile 64x64

  // bijective XCD swizzle (m204); n-tile fastest
  const int nwg  = gridDim.x * gridDim.y;
  const int orig = blockIdx.x + gridDim.x * blockIdx.y;
  const int q = nwg >> 3, r = nwg & 7;
  const int xcd = orig & 7, seq = orig >> 3;
  const int wg = (xcd < r ? xcd * (q + 1) : r * (q + 1) + (xcd - r) * q) + seq;
  const int mt = wg >> 1, nt = wg & 1;        // NT = 2
  const int m0 = mt * 128, n0 = nt * 256;

  f32x4 acc[4][4];
#pragma unroll
  for (int i = 0; i < 4; ++i)
#pragma unroll
    for (int j = 0; j < 4; ++j) acc[i][j] = (f32x4){0.f, 0.f, 0.f, 0.f};

  // A staging: wave w stages m-frag w (rows m0 + w*16 + l15)
  const int arow = min(m0 + w * 16 + l15, M - 1);
  const int kl = l4 * 8;
  const u16* pA1 = A1 + (size_t)arow * DIN + kl;
  const u16* pA2 = A2 + (size_t)arow * DIN + kl;
  // B staging (fragment-packed): wave w stages n-frags {2w, 2w+1}
  const u16* bb1 = Wt1 + ((size_t)(n0 >> 4) + 2 * w) * KS * 512 + (size_t)l * 8;
  const u16* bb2 = Wt2 + ((size_t)(n0 >> 4) + 2 * w) * KS * 512 + (size_t)l * 8;

  auto stage = [&](int s) {                    // 3 global_load_lds per wave
    const int ph = s / KS;
    const int kf = s - ph * KS;
    char* buf = lds + (s % 3) * 24576;
    const u16* a0 = (ph ? pA2 : pA1) + kf * 32;
    const u16* b0 = (ph ? bb2 : bb1) + kf * 512;
    const u16* b1 = b0 + KS * 512;             // next n-frag
    __builtin_amdgcn_global_load_lds(GLOBAL_AS(a0), LDS_AS(buf + w * 1024), 16, 0, 0);
    __builtin_amdgcn_global_load_lds(GLOBAL_AS(b0), LDS_AS(buf + 8192 + (2 * w + 0) * 1024), 16, 0, 0);
    __builtin_amdgcn_global_load_lds(GLOBAL_AS(b1), LDS_AS(buf + 8192 + (2 * w + 1) * 1024), 16, 0, 0);
  };

  stage(0);
  stage(1);
  stage(2);

#pragma unroll
  for (int s = 0; s < S; ++s) {
    const int rem = S - 1 - s;
    if (rem >= 2)      asm volatile("s_waitcnt vmcnt(6)" ::: "memory");
    else if (rem == 1) asm volatile("s_waitcnt vmcnt(3)" ::: "memory");
    else               asm volatile("s_waitcnt vmcnt(0)" ::: "memory");
    __builtin_amdgcn_s_barrier();
    char* buf = lds + (s % 3) * 24576;
    bf16x8 af[4], bfr[4];
#pragma unroll
    for (int i = 0; i < 4; ++i)
      af[i] = *reinterpret_cast<const bf16x8*>(buf + (wm * 4 + i) * 1024 + l * 16);
#pragma unroll
    for (int j = 0; j < 4; ++j)
      bfr[j] = *reinterpret_cast<const bf16x8*>(buf + 8192 + (wn * 4 + j) * 1024 + l * 16);
#pragma unroll
    for (int i = 0; i < 4; ++i)
#pragma unroll
      for (int j = 0; j < 4; ++j)
        acc[i][j] = __builtin_amdgcn_mfma_f32_16x16x32_bf16(af[i], bfr[j], acc[i][j], 0, 0, 0);
    asm volatile("s_waitcnt lgkmcnt(0)" ::: "memory");   // all reads of buf retired
    __builtin_amdgcn_s_barrier();
    if (s + 3 < S) stage(s + 3);
  }

  // ---- coalesced epilogue: C/D (col=lane&15, row=(lane>>4)*4+reg) -> LDS -> global ----
  // wave region: 64 rows x 72 u16 (144B rows: 16B-aligned, 2-way-max bank alias)
  u16* eb = (u16*)(lds + w * 9216);
  float bv[4];
#pragma unroll
  for (int j = 0; j < 4; ++j) bv[j] = bias[n0 + wn * 64 + j * 16 + l15];
#pragma unroll
  for (int i = 0; i < 4; ++i)
#pragma unroll
    for (int j = 0; j < 4; ++j)
#pragma unroll
      for (int r = 0; r < 4; ++r) {
        const int lr = i * 16 + l4 * 4 + r;
        float t = acc[i][j][r] + bv[j];
        if (RELU) t = fmaxf(t, 0.f);
        eb[lr * 72 + j * 16 + l15] = f2bf(t);
      }
  asm volatile("s_waitcnt lgkmcnt(0)" ::: "memory");      // wave-local write->read order
#pragma unroll
  for (int p = 0; p < 8; ++p) {
    const int lr = p * 8 + (l >> 3);
    const int row = m0 + wm * 64 + lr;
    if (row < M) {
      const uint4 v = *reinterpret_cast<const uint4*>(eb + lr * 72 + (l & 7) * 8);
      *reinterpret_cast<uint4*>(out + (size_t)row * DOUT + n0 + wn * 64 + (l & 7) * 8) = v;
    }
  }
}

// -------- 128x128 4-wave 3-deep kernel (DOUT=128, optional A1-row remap — L4) ----------
template <int DIN, int DOUT, bool RELU, bool REMAP>
__global__ __launch_bounds__(256, 3)
void k_gemm(const u16* __restrict__ A1, const u16* __restrict__ A2,
            const u16* __restrict__ Wt1, const u16* __restrict__ Wt2,
            const float* __restrict__ bias, u16* __restrict__ out, int M,
            const int* __restrict__ remap) {
  __shared__ char lds[49152];
  constexpr int KS = DIN / 32;
  constexpr int S  = 2 * KS;
  const int tid = threadIdx.x;
  const int w = tid >> 6, l = tid & 63;
  const int l15 = l & 15, l4 = l >> 4;
  const int wm = w >> 1, wn = w & 1;

  const int nwg  = gridDim.x * gridDim.y;
  const int orig = blockIdx.x + gridDim.x * blockIdx.y;
  const int q = nwg >> 3, r = nwg & 7;
  const int xcd = orig & 7, seq = orig >> 3;
  const int wg = (xcd < r ? xcd * (q + 1) : r * (q + 1) + (xcd - r) * q) + seq;
  constexpr int NT = DOUT / 128;
  const int mt = wg / NT, nt = wg - mt * NT;
  const int m0 = mt * 128, n0 = nt * 128;

  f32x4 acc[4][4];
#pragma unroll
  for (int i = 0; i < 4; ++i)
#pragma unroll
    for (int j = 0; j < 4; ++j) acc[i][j] = (f32x4){0.f, 0.f, 0.f, 0.f};

  const int am0 = min(m0 + (2 * w) * 16 + l15, M - 1);
  const int am1 = min(m0 + (2 * w + 1) * 16 + l15, M - 1);
  const int ar0 = REMAP ? remap[am0] : am0;
  const int ar1 = REMAP ? remap[am1] : am1;
  const int kl = l4 * 8;
  const u16* pA1r0 = A1 + (size_t)ar0 * DIN + kl;
  const u16* pA1r1 = A1 + (size_t)ar1 * DIN + kl;
  const u16* pA2r0 = A2 + (size_t)am0 * DIN + kl;
  const u16* pA2r1 = A2 + (size_t)am1 * DIN + kl;
  const u16* bb1 = Wt1 + ((size_t)(n0 >> 4) + 2 * w) * KS * 512 + (size_t)l * 8;
  const u16* bb2 = Wt2 + ((size_t)(n0 >> 4) + 2 * w) * KS * 512 + (size_t)l * 8;

  auto stage = [&](int s) {
    const int ph = s / KS;
    const int kf = s - ph * KS;
    char* buf = lds + (s % 3) * 16384;
    const u16* a0 = (ph ? pA2r0 : pA1r0) + kf * 32;
    const u16* a1 = (ph ? pA2r1 : pA1r1) + kf * 32;
    const u16* b0 = (ph ? bb2 : bb1) + kf * 512;
    const u16* b1 = b0 + KS * 512;
    __builtin_amdgcn_global_load_lds(GLOBAL_AS(a0), LDS_AS(buf + (2 * w + 0) * 1024), 16, 0, 0);
    __builtin_amdgcn_global_load_lds(GLOBAL_AS(a1), LDS_AS(buf + (2 * w + 1) * 1024), 16, 0, 0);
    __builtin_amdgcn_global_load_lds(GLOBAL_AS(b0), LDS_AS(buf + 8192 + (2 * w + 0) * 1024), 16, 0, 0);
    __builtin_amdgcn_global_load_lds(GLOBAL_AS(b1), LDS_AS(buf + 8192 + (2 * w + 1) * 1024), 16, 0, 0);
  };

  stage(0);
  stage(1);
  stage(2);

#pragma unroll
  for (int s = 0; s < S; ++s) {
    const int rem = S - 1 - s;
    if (rem >= 2)      asm volatile("s_waitcnt vmcnt(8)" ::: "memory");
    else if (rem == 1) asm volatile("s_waitcnt vmcnt(4)" ::: "memory");
    else               asm volatile("s_waitcnt vmcnt(0)" ::: "memory");
    __builtin_amdgcn_s_barrier();
    char* buf = lds + (s % 3) * 16384;
    bf16x8 af[4], bfr[4];
#pragma unroll
    for (int i = 0; i < 4; ++i)
      af[i] = *reinterpret_cast<const bf16x8*>(buf + (wm * 4 + i) * 1024 + l * 16);
#pragma unroll
    for (int j = 0; j < 4; ++j)
      bfr[j] = *reinterpret_cast<const bf16x8*>(buf + 8192 + (wn * 4 + j) * 1024 + l * 16);
#pragma unroll
    for (int i = 0; i < 4; ++i)
#pragma unroll
      for (int j = 0; j < 4; ++j)
        acc[i][j] = __builtin_amdgcn_mfma_f32_16x16x32_bf16(af[i], bfr[j], acc[i][j], 0, 0, 0);
    asm volatile("s_waitcnt lgkmcnt(0)" ::: "memory");
    __builtin_amdgcn_s_barrier();
    if (s + 3 < S) stage(s + 3);
  }

#pragma unroll
  for (int j = 0; j < 4; ++j) {
    const int c = n0 + wn * 64 + j * 16 + l15;
    const float bv = bias[c];
#pragma unroll
    for (int i = 0; i < 4; ++i) {
      const int rowb = m0 + wm * 64 + i * 16 + l4 * 4;
#pragma unroll
      for (int r = 0; r < 4; ++r) {
        const int row = rowb + r;
        if (row < M) {
          float t = acc[i][j][r] + bv;
          if (RELU) t = fmaxf(t, 0.f);
          out[(size_t)row * DOUT + c] = f2bf(t);
        }
      }
    }
  }
}

// ---------------- loss (dec is COMPACT: NM x 128, slot m <-> node mask[m]) -------------
__global__ __launch_bounds__(256)
void k_loss1(const u16* __restrict__ dec, const float* __restrict__ attr,
             const int* __restrict__ mask, int NM, float* __restrict__ partials) {
  __shared__ float sm[256];
  float s = 0.f;
  const int total = NM * (IN_DIM / 4);
  for (int idx = blockIdx.x * blockDim.x + threadIdx.x; idx < total; idx += gridDim.x * blockDim.x) {
    const int m = idx >> 5, c = (idx & 31) * 4;
    const int node = mask[m];
    const float4 a = *reinterpret_cast<const float4*>(&attr[(size_t)node * IN_DIM + c]);
    const uint2 d2 = *reinterpret_cast<const uint2*>(&dec[(size_t)m * IN_DIM + c]);
    const float dx = bfu2f(d2.x & 0xffffu) - a.x;
    const float dy = bfu2f(d2.x >> 16)     - a.y;
    const float dz = bfu2f(d2.y & 0xffffu) - a.z;
    const float dw = bfu2f(d2.y >> 16)     - a.w;
    s += dx * dx + dy * dy + dz * dz + dw * dw;
  }
  sm[threadIdx.x] = s;
  __syncthreads();
  for (int off = 128; off > 0; off >>= 1) {
    if (threadIdx.x < off) sm[threadIdx.x] += sm[threadIdx.x + off];
    __syncthreads();
  }
  if (threadIdx.x == 0) partials[blockIdx.x] = sm[0];
}

__global__ __launch_bounds__(256)
void k_loss2(const float* __restrict__ partials, int nb, float* __restrict__ out, float inv) {
  __shared__ float sm[256];
  float s = 0.f;
  for (int i = threadIdx.x; i < nb; i += 256) s += partials[i];
  sm[threadIdx.x] = s;
  __syncthreads();
  for (int off = 128; off > 0; off >>= 1) {
    if (threadIdx.x < off) sm[threadIdx.x] += sm[threadIdx.x + off];
    __syncthreads();
  }
  if (threadIdx.x == 0) out[0] = sm[0] * inv;
}

// ---------------- launch ----------------
extern "C" void kernel_launch(void* const* d_in, const int* in_sizes, int n_in,
                              void* d_out, int out_size, void* d_ws, size_t ws_size,
                              hipStream_t stream) {
  const float* attr  = (const float*)d_in[0];
  const float* token = (const float*)d_in[1];
  const int*   src   = (const int*)d_in[2];
  const int*   dst   = (const int*)d_in[3];
  const int*   mask  = (const int*)d_in[4];
  const float* Wself[4]  = {(const float*)d_in[5], (const float*)d_in[8],
                            (const float*)d_in[11], (const float*)d_in[14]};
  const float* Wneigh[4] = {(const float*)d_in[6], (const float*)d_in[9],
                            (const float*)d_in[12], (const float*)d_in[15]};
  const float* Bias[4]   = {(const float*)d_in[7], (const float*)d_in[10],
                            (const float*)d_in[13], (const float*)d_in[16]};
  const int N  = in_sizes[0] / IN_DIM;
  const int E  = in_sizes[2];
  const int NM = in_sizes[4];

  size_t off = 0;
  auto take = [&](size_t bytes) -> void* {
    void* p = (char*)d_ws + off;
    off += (bytes + 255) & ~(size_t)255;
    return p;
  };
  u16* HA = (u16*)take((size_t)N * HID * sizeof(u16));   // 51.2 MB
  u16* HB = (u16*)take((size_t)N * HID * sizeof(u16));   // 51.2 MB
  const int dims_in[4]  = {IN_DIM, HID, HID, HID};
  const int dims_out[4] = {HID, HID, HID, IN_DIM};
  u16* WtS[4]; u16* WtN[4];
  for (int i = 0; i < 4; ++i) {
    WtS[i] = (u16*)take((size_t)dims_in[i] * dims_out[i] * sizeof(u16));
    WtN[i] = (u16*)take((size_t)dims_in[i] * dims_out[i] * sizeof(u16));
  }
  int* deg    = (int*)take((size_t)N * sizeof(int));
  int* rowptr = (int*)take((size_t)(N + 1) * sizeof(int));
  int* cursor = (int*)take((size_t)N * sizeof(int));
  int* col    = (int*)take((size_t)E * sizeof(int));
  float* partials = (float*)take(512 * sizeof(float));

  // agg chunk: one chunk covering N (rounded to 256)
  size_t rem = (ws_size > off + 4096) ? (ws_size - off - 4096) : 0;
  const int cap = (int)(rem / ((size_t)HID * sizeof(u16)));
  const int want = (N + 255) & ~255;
  int chunk = (cap >= want) ? want : (cap & ~255);
  if (chunk < 2048) chunk = 2048;
  u16* CH = (u16*)take((size_t)chunk * HID * sizeof(u16));
  u16* DEC = HA;                               // decoded compact (NM x 128) reuses HA

  // CSR build
  k_zero<<<imin_h((N + 255) / 256, 1024), 256, 0, stream>>>(deg, N);
  const int eb = imin_h((E + 255) / 256, 4096);
  k_hist<<<eb, 256, 0, stream>>>(dst, deg, E);
  k_scan<<<1, 1024, 0, stream>>>(deg, rowptr, cursor, N);
  k_fill<<<eb, 256, 0, stream>>>(src, dst, cursor, col, E);

  // weights: transpose + bf16 + fragment-pack once per call
  for (int i = 0; i < 4; ++i) {
    const int tot = dims_in[i] * dims_out[i];
    k_wt<<<imin_h((tot + 255) / 256, 2048), 256, 0, stream>>>(Wself[i],  WtS[i], dims_in[i], dims_out[i]);
    k_wt<<<imin_h((tot + 255) / 256, 2048), 256, 0, stream>>>(Wneigh[i], WtN[i], dims_in[i], dims_out[i]);
  }

  // h0 = bf16(attr) with masked rows = token   (in HA as N x 128)
  const int n4 = N * (IN_DIM / 4);
  k_cvt<<<imin_h((n4 + 255) / 256, 2048), 256, 0, stream>>>((const float4*)attr, (uint2*)HA, n4);
  k_mask<<<imin_h((NM * (IN_DIM / 4) + 255) / 256, 2048), 256, 0, stream>>>(
      (const float4*)token, mask, (uint2*)HA, NM);

  // L1..L3 (full N, DOUT=512): agg chunk -> big gemm (128x256 tiles)
  auto run_layer = [&](const u16* hin, u16* hout, int din, int layer, bool relu) {
    for (int c0 = 0; c0 < N; c0 += chunk) {
      const int mc = imin_h(chunk, N - c0);
      const int ab = (mc + 3) / 4;
      if (din == IN_DIM)
        k_agg<IN_DIM, false><<<ab, 256, 0, stream>>>(hin, col, rowptr + c0, nullptr, CH, mc);
      else
        k_agg<HID, false><<<ab, 256, 0, stream>>>(hin, col, rowptr + c0, nullptr, CH, mc);
      const u16* a1 = hin + (size_t)c0 * din;
      u16* o = hout + (size_t)c0 * HID;
      const int mb = (mc + 127) / 128;
      if (din == IN_DIM && relu)
        k_gemm_big<IN_DIM, true><<<dim3(2, mb), 512, 0, stream>>>(
            a1, CH, WtS[layer], WtN[layer], Bias[layer], o, mc);
      else if (relu)
        k_gemm_big<HID, true><<<dim3(2, mb), 512, 0, stream>>>(
            a1, CH, WtS[layer], WtN[layer], Bias[layer], o, mc);
      else
        k_gemm_big<HID, false><<<dim3(2, mb), 512, 0, stream>>>(
            a1, CH, WtS[layer], WtN[layer], Bias[layer], o, mc);
    }
  };

  run_layer(HA, HB, IN_DIM, 0, true);   // L1: 128->512 relu   (HA h0 -> HB h1)
  run_layer(HB, HA, HID,    1, false);  // L2: 512->512        (HB h1 -> HA h2)
  run_layer(HA, HB, HID,    2, true);   // L3: 512->512 relu   (HA h2 -> HB h3)

  // L4 mask-restricted: decoded only at mask nodes (compact NM rows)
  k_agg<HID, true><<<(NM + 3) / 4, 256, 0, stream>>>(HB, col, rowptr, mask, CH, NM);
  k_gemm<HID, IN_DIM, false, true><<<dim3(1, (NM + 127) / 128), 256, 0, stream>>>(
      HB, CH, WtS[3], WtN[3], Bias[3], DEC, NM, mask);

  // loss = mean((decoded[mask] - attr[mask])^2)
  k_loss1<<<512, 256, 0, stream>>>(DEC, attr, mask, NM, partials);
  k_loss2<<<1, 256, 0, stream>>>(partials, 512, (float*)d_out, 1.0f / ((float)NM * IN_DIM));
}

// Round 12
// 456.496 us; speedup vs baseline: 1.6403x; 1.1736x over previous
//
#include <hip/hip_runtime.h>
#include <cstdint>
#include <cstddef>

#define IN_DIM 128
#define HID    512

typedef unsigned int   uint32;
typedef unsigned short u16;
typedef __attribute__((ext_vector_type(8))) short bf16x8;   // 8 bf16 (4 VGPRs)
typedef __attribute__((ext_vector_type(4))) float f32x4;

static inline int imin_h(int a, int b) { return a < b ? a : b; }

// ---- bf16 helpers (storage-only bf16; accumulation fp32) ----
__device__ __forceinline__ float bfu2f(uint32 u) { return __uint_as_float(u << 16); }
__device__ __forceinline__ u16 f2bf(float f) {
  uint32 x = __float_as_uint(f);
  x += 0x7fffu + ((x >> 16) & 1u);           // round-to-nearest-even
  return (u16)(x >> 16);
}
__device__ __forceinline__ uint32 pack2(float a, float b) {
  return (uint32)f2bf(a) | ((uint32)f2bf(b) << 16);
}

#define GLOBAL_AS(p) ((const __attribute__((address_space(1))) void*)(p))
#define LDS_AS(p)    ((__attribute__((address_space(3))) void*)(p))

// ---------------- misc ----------------
__global__ void k_zero(int* __restrict__ p, int n) {
  for (int i = blockIdx.x * blockDim.x + threadIdx.x; i < n; i += gridDim.x * blockDim.x)
    p[i] = 0;
}

// ---------------- CSR build (by dst) ----------------
__global__ void k_hist(const int* __restrict__ dst, int* __restrict__ deg, int E) {
  for (int e = blockIdx.x * blockDim.x + threadIdx.x; e < E; e += gridDim.x * blockDim.x)
    atomicAdd(&deg[dst[e]], 1);
}

// ---- 3-phase multi-block exclusive scan (chunk = 2048 = 256 thr x 8) ----
__global__ __launch_bounds__(256)
void k_scan1(const int* __restrict__ deg, int* __restrict__ bsum, int n) {
  __shared__ int sm[256];
  const int base = blockIdx.x * 2048 + threadIdx.x * 8;
  int s = 0;
  if (base + 8 <= n) {
    const uint4 a = *reinterpret_cast<const uint4*>(deg + base);
    const uint4 b = *reinterpret_cast<const uint4*>(deg + base + 4);
    s = (int)(a.x + a.y + a.z + a.w + b.x + b.y + b.z + b.w);
  } else {
    for (int i = 0; i < 8; ++i) if (base + i < n) s += deg[base + i];
  }
  sm[threadIdx.x] = s;
  __syncthreads();
  for (int off = 128; off > 0; off >>= 1) {
    if (threadIdx.x < off) sm[threadIdx.x] += sm[threadIdx.x + off];
    __syncthreads();
  }
  if (threadIdx.x == 0) bsum[blockIdx.x] = sm[0];
}

// single block: exclusive scan of nb (<=256) block sums in place; writes rowptr[n]=total
__global__ __launch_bounds__(256)
void k_scan2(int* __restrict__ bsum, int nb, int* __restrict__ rowptr, int n) {
  __shared__ int sm[256];
  const int v = (threadIdx.x < nb) ? bsum[threadIdx.x] : 0;
  sm[threadIdx.x] = v;
  __syncthreads();
  for (int off = 1; off < 256; off <<= 1) {
    const int t = (threadIdx.x >= off) ? sm[threadIdx.x - off] : 0;
    __syncthreads();
    sm[threadIdx.x] += t;
    __syncthreads();
  }
  if (threadIdx.x < nb) bsum[threadIdx.x] = sm[threadIdx.x] - v;  // exclusive
  if (threadIdx.x == nb - 1) rowptr[n] = sm[threadIdx.x];          // total = E
}

__global__ __launch_bounds__(256)
void k_scan3(const int* __restrict__ deg, const int* __restrict__ bsum,
             int* __restrict__ rowptr, int* __restrict__ cursor, int n) {
  __shared__ int sm[256];
  const int base = blockIdx.x * 2048 + threadIdx.x * 8;
  int v[8];
  int s = 0;
#pragma unroll
  for (int i = 0; i < 8; ++i) {
    v[i] = (base + i < n) ? deg[base + i] : 0;
    s += v[i];
  }
  sm[threadIdx.x] = s;
  __syncthreads();
  for (int off = 1; off < 256; off <<= 1) {
    const int t = (threadIdx.x >= off) ? sm[threadIdx.x - off] : 0;
    __syncthreads();
    sm[threadIdx.x] += t;
    __syncthreads();
  }
  int run = bsum[blockIdx.x] + sm[threadIdx.x] - s;   // exclusive prefix for this thread
#pragma unroll
  for (int i = 0; i < 8; ++i) {
    if (base + i < n) { rowptr[base + i] = run; cursor[base + i] = run; }
    run += v[i];
  }
}

__global__ void k_fill(const int* __restrict__ src, const int* __restrict__ dst,
                       int* __restrict__ cursor, int* __restrict__ col, int E) {
  for (int e = blockIdx.x * blockDim.x + threadIdx.x; e < E; e += gridDim.x * blockDim.x) {
    const int p = atomicAdd(&cursor[dst[e]], 1);
    col[p] = src[e];
  }
}

// ---------------- h0 = bf16(attr); masked rows = token ----------------
__global__ void k_cvt(const float4* __restrict__ in, uint2* __restrict__ out, int n4) {
  for (int i = blockIdx.x * blockDim.x + threadIdx.x; i < n4; i += gridDim.x * blockDim.x) {
    const float4 v = in[i];
    out[i] = make_uint2(pack2(v.x, v.y), pack2(v.z, v.w));
  }
}

__global__ void k_mask(const float4* __restrict__ token, const int* __restrict__ mask,
                       uint2* __restrict__ h0, int NM) {
  const int total = NM * (IN_DIM / 4);
  for (int i = blockIdx.x * blockDim.x + threadIdx.x; i < total; i += gridDim.x * blockDim.x) {
    const int m = i >> 5;
    const int c = i & 31;
    const float4 t = token[c];
    h0[(size_t)mask[m] * (IN_DIM / 4) + c] = make_uint2(pack2(t.x, t.y), pack2(t.z, t.w));
  }
}

// ------- weight transpose + convert + FRAGMENT-PACK ----------------------------------
// frag f = (n>>4)*(K/32) + (k>>5); u16 idx = f*512 + ((k>>3)&3)*128 + (n&15)*8 + (k&7).
__global__ void k_wt(const float* __restrict__ W, u16* __restrict__ Wt, int K, int Nn) {
  const int total = K * Nn;
  for (int t = blockIdx.x * blockDim.x + threadIdx.x; t < total; t += gridDim.x * blockDim.x) {
    const int n = t / K, k = t - n * K;
    const size_t idx = ((size_t)(n >> 4) * (K >> 5) + (k >> 5)) * 512 +
                       ((k >> 3) & 3) * 128 + ((n & 15) << 3) + (k & 7);
    Wt[idx] = f2bf(W[(size_t)k * Nn + n]);
  }
}

// -------- mean aggregation over in-neighbors (CSR gather, 1 wave/node, 2-deep) --------
template <int D, bool REMAP>
__global__ __launch_bounds__(256)
void k_agg(const u16* __restrict__ h, const int* __restrict__ col,
           const int* __restrict__ rowptr, const int* __restrict__ nodes,
           u16* __restrict__ out, int n) {
  constexpr int V = D / 64;
  const int w = blockIdx.x * (blockDim.x >> 6) + (threadIdx.x >> 6);
  if (w >= n) return;
  const int node = REMAP ? nodes[w] : w;
  const int lane = threadIdx.x & 63;
  const int beg = rowptr[node], end = rowptr[node + 1];
  const size_t loff = (size_t)lane * V;
  float acc[V];
#pragma unroll
  for (int j = 0; j < V; ++j) acc[j] = 0.f;
  if constexpr (V == 8) {
    uint4 cur;
    if (beg < end) cur = *reinterpret_cast<const uint4*>(h + (size_t)col[beg] * D + loff);
    for (int e = beg; e < end; ++e) {
      uint4 nxt = cur;
      if (e + 1 < end)
        nxt = *reinterpret_cast<const uint4*>(h + (size_t)col[e + 1] * D + loff);
      acc[0] += bfu2f(cur.x & 0xffffu); acc[1] += bfu2f(cur.x >> 16);
      acc[2] += bfu2f(cur.y & 0xffffu); acc[3] += bfu2f(cur.y >> 16);
      acc[4] += bfu2f(cur.z & 0xffffu); acc[5] += bfu2f(cur.z >> 16);
      acc[6] += bfu2f(cur.w & 0xffffu); acc[7] += bfu2f(cur.w >> 16);
      cur = nxt;
    }
  } else {
    uint32 cur = 0;
    if (beg < end) cur = *reinterpret_cast<const uint32*>(h + (size_t)col[beg] * D + loff);
    for (int e = beg; e < end; ++e) {
      uint32 nxt = cur;
      if (e + 1 < end)
        nxt = *reinterpret_cast<const uint32*>(h + (size_t)col[e + 1] * D + loff);
      acc[0] += bfu2f(cur & 0xffffu); acc[1] += bfu2f(cur >> 16);
      cur = nxt;
    }
  }
  const float inv = 1.0f / fmaxf((float)(end - beg), 1.0f);
  u16* o = out + (size_t)w * D + loff;
  if constexpr (V == 8) {
    uint4 u;
    u.x = pack2(acc[0] * inv, acc[1] * inv);
    u.y = pack2(acc[2] * inv, acc[3] * inv);
    u.z = pack2(acc[4] * inv, acc[5] * inv);
    u.w = pack2(acc[6] * inv, acc[7] * inv);
    *reinterpret_cast<uint4*>(o) = u;
  } else {
    *reinterpret_cast<uint32*>(o) = pack2(acc[0] * inv, acc[1] * inv);
  }
}

// ======== dual-A bf16 MFMA GEMM: 128x256 tile, 8 waves of 64x64, 2 blocks/CU ===========
// out = bf16(A1@W1 + A2@W2 + b), opt ReLU.  DOUT = 512 (NT = 2 n-tiles of 256).
// acc = 64 regs/wave -> <=128 unified regs -> 4 waves/SIMD -> 2 co-resident blocks/CU.
// 3 rotating 24KB LDS buffers (72KB). 3 loads/wave/step; prefetch 2, vmcnt(6/3/0).
// Epilogue: C -> LDS (bf16, 72-u16 padded rows) -> 16B/lane coalesced global stores.
template <int DIN, bool RELU>
__global__ __launch_bounds__(512, 4)
void k_gemm_big(const u16* __restrict__ A1, const u16* __restrict__ A2,
                const u16* __restrict__ Wt1, const u16* __restrict__ Wt2,
                const float* __restrict__ bias, u16* __restrict__ out, int M) {
  constexpr int DOUT = HID;
  __shared__ char lds[73728];                 // 3 x (A 8KB + B 16KB); epilogue: 8 x 9216B
  constexpr int KS = DIN / 32;                // k-frags per phase
  constexpr int S  = 2 * KS;                  // total K-steps (dual-A)
  const int tid = threadIdx.x;
  const int w = tid >> 6, l = tid & 63;
  const int l15 = l & 15, l4 = l >> 4;
  const int wm = w >> 2, wn = w & 3;          // 2 x 4 wave grid, wave tile 64x64

  // bijective XCD swizzle (m204); n-tile fastest
  const int nwg  = gridDim.x * gridDim.y;
  const int orig = blockIdx.x + gridDim.x * blockIdx.y;
  const int q = nwg >> 3, r = nwg & 7;
  const int xcd = orig & 7, seq = orig >> 3;
  const int wg = (xcd < r ? xcd * (q + 1) : r * (q + 1) + (xcd - r) * q) + seq;
  const int mt = wg >> 1, nt = wg & 1;        // NT = 2
  const int m0 = mt * 128, n0 = nt * 256;

  f32x4 acc[4][4];
#pragma unroll
  for (int i = 0; i < 4; ++i)
#pragma unroll
    for (int j = 0; j < 4; ++j) acc[i][j] = (f32x4){0.f, 0.f, 0.f, 0.f};

  // A staging: wave w stages m-frag w (rows m0 + w*16 + l15)
  const int arow = min(m0 + w * 16 + l15, M - 1);
  const int kl = l4 * 8;
  const u16* pA1 = A1 + (size_t)arow * DIN + kl;
  const u16* pA2 = A2 + (size_t)arow * DIN + kl;
  // B staging (fragment-packed): wave w stages n-frags {2w, 2w+1}
  const u16* bb1 = Wt1 + ((size_t)(n0 >> 4) + 2 * w) * KS * 512 + (size_t)l * 8;
  const u16* bb2 = Wt2 + ((size_t)(n0 >> 4) + 2 * w) * KS * 512 + (size_t)l * 8;

  auto stage = [&](int s) {                    // 3 global_load_lds per wave
    const int ph = s / KS;
    const int kf = s - ph * KS;
    char* buf = lds + (s % 3) * 24576;
    const u16* a0 = (ph ? pA2 : pA1) + kf * 32;
    const u16* b0 = (ph ? bb2 : bb1) + kf * 512;
    const u16* b1 = b0 + KS * 512;             // next n-frag
    __builtin_amdgcn_global_load_lds(GLOBAL_AS(a0), LDS_AS(buf + w * 1024), 16, 0, 0);
    __builtin_amdgcn_global_load_lds(GLOBAL_AS(b0), LDS_AS(buf + 8192 + (2 * w + 0) * 1024), 16, 0, 0);
    __builtin_amdgcn_global_load_lds(GLOBAL_AS(b1), LDS_AS(buf + 8192 + (2 * w + 1) * 1024), 16, 0, 0);
  };

  stage(0);
  stage(1);
  stage(2);

#pragma unroll
  for (int s = 0; s < S; ++s) {
    const int rem = S - 1 - s;
    if (rem >= 2)      asm volatile("s_waitcnt vmcnt(6)" ::: "memory");
    else if (rem == 1) asm volatile("s_waitcnt vmcnt(3)" ::: "memory");
    else               asm volatile("s_waitcnt vmcnt(0)" ::: "memory");
    __builtin_amdgcn_s_barrier();
    char* buf = lds + (s % 3) * 24576;
    bf16x8 af[4], bfr[4];
#pragma unroll
    for (int i = 0; i < 4; ++i)
      af[i] = *reinterpret_cast<const bf16x8*>(buf + (wm * 4 + i) * 1024 + l * 16);
#pragma unroll
    for (int j = 0; j < 4; ++j)
      bfr[j] = *reinterpret_cast<const bf16x8*>(buf + 8192 + (wn * 4 + j) * 1024 + l * 16);
#pragma unroll
    for (int i = 0; i < 4; ++i)
#pragma unroll
      for (int j = 0; j < 4; ++j)
        acc[i][j] = __builtin_amdgcn_mfma_f32_16x16x32_bf16(af[i], bfr[j], acc[i][j], 0, 0, 0);
    asm volatile("s_waitcnt lgkmcnt(0)" ::: "memory");   // all reads of buf retired
    __builtin_amdgcn_s_barrier();
    if (s + 3 < S) stage(s + 3);
  }

  // ---- coalesced epilogue: C/D (col=lane&15, row=(lane>>4)*4+reg) -> LDS -> global ----
  u16* eb = (u16*)(lds + w * 9216);
  float bv[4];
#pragma unroll
  for (int j = 0; j < 4; ++j) bv[j] = bias[n0 + wn * 64 + j * 16 + l15];
#pragma unroll
  for (int i = 0; i < 4; ++i)
#pragma unroll
    for (int j = 0; j < 4; ++j)
#pragma unroll
      for (int r = 0; r < 4; ++r) {
        const int lr = i * 16 + l4 * 4 + r;
        float t = acc[i][j][r] + bv[j];
        if (RELU) t = fmaxf(t, 0.f);
        eb[lr * 72 + j * 16 + l15] = f2bf(t);
      }
  asm volatile("s_waitcnt lgkmcnt(0)" ::: "memory");      // wave-local write->read order
#pragma unroll
  for (int p = 0; p < 8; ++p) {
    const int lr = p * 8 + (l >> 3);
    const int row = m0 + wm * 64 + lr;
    if (row < M) {
      const uint4 v = *reinterpret_cast<const uint4*>(eb + lr * 72 + (l & 7) * 8);
      *reinterpret_cast<uint4*>(out + (size_t)row * DOUT + n0 + wn * 64 + (l & 7) * 8) = v;
    }
  }
}

// -------- 128x128 4-wave 3-deep kernel (DOUT=128, optional A1-row remap — L4) ----------
template <int DIN, int DOUT, bool RELU, bool REMAP>
__global__ __launch_bounds__(256, 3)
void k_gemm(const u16* __restrict__ A1, const u16* __restrict__ A2,
            const u16* __restrict__ Wt1, const u16* __restrict__ Wt2,
            const float* __restrict__ bias, u16* __restrict__ out, int M,
            const int* __restrict__ remap) {
  __shared__ char lds[49152];
  constexpr int KS = DIN / 32;
  constexpr int S  = 2 * KS;
  const int tid = threadIdx.x;
  const int w = tid >> 6, l = tid & 63;
  const int l15 = l & 15, l4 = l >> 4;
  const int wm = w >> 1, wn = w & 1;

  const int nwg  = gridDim.x * gridDim.y;
  const int orig = blockIdx.x + gridDim.x * blockIdx.y;
  const int q = nwg >> 3, r = nwg & 7;
  const int xcd = orig & 7, seq = orig >> 3;
  const int wg = (xcd < r ? xcd * (q + 1) : r * (q + 1) + (xcd - r) * q) + seq;
  constexpr int NT = DOUT / 128;
  const int mt = wg / NT, nt = wg - mt * NT;
  const int m0 = mt * 128, n0 = nt * 128;

  f32x4 acc[4][4];
#pragma unroll
  for (int i = 0; i < 4; ++i)
#pragma unroll
    for (int j = 0; j < 4; ++j) acc[i][j] = (f32x4){0.f, 0.f, 0.f, 0.f};

  const int am0 = min(m0 + (2 * w) * 16 + l15, M - 1);
  const int am1 = min(m0 + (2 * w + 1) * 16 + l15, M - 1);
  const int ar0 = REMAP ? remap[am0] : am0;
  const int ar1 = REMAP ? remap[am1] : am1;
  const int kl = l4 * 8;
  const u16* pA1r0 = A1 + (size_t)ar0 * DIN + kl;
  const u16* pA1r1 = A1 + (size_t)ar1 * DIN + kl;
  const u16* pA2r0 = A2 + (size_t)am0 * DIN + kl;
  const u16* pA2r1 = A2 + (size_t)am1 * DIN + kl;
  const u16* bb1 = Wt1 + ((size_t)(n0 >> 4) + 2 * w) * KS * 512 + (size_t)l * 8;
  const u16* bb2 = Wt2 + ((size_t)(n0 >> 4) + 2 * w) * KS * 512 + (size_t)l * 8;

  auto stage = [&](int s) {
    const int ph = s / KS;
    const int kf = s - ph * KS;
    char* buf = lds + (s % 3) * 16384;
    const u16* a0 = (ph ? pA2r0 : pA1r0) + kf * 32;
    const u16* a1 = (ph ? pA2r1 : pA1r1) + kf * 32;
    const u16* b0 = (ph ? bb2 : bb1) + kf * 512;
    const u16* b1 = b0 + KS * 512;
    __builtin_amdgcn_global_load_lds(GLOBAL_AS(a0), LDS_AS(buf + (2 * w + 0) * 1024), 16, 0, 0);
    __builtin_amdgcn_global_load_lds(GLOBAL_AS(a1), LDS_AS(buf + (2 * w + 1) * 1024), 16, 0, 0);
    __builtin_amdgcn_global_load_lds(GLOBAL_AS(b0), LDS_AS(buf + 8192 + (2 * w + 0) * 1024), 16, 0, 0);
    __builtin_amdgcn_global_load_lds(GLOBAL_AS(b1), LDS_AS(buf + 8192 + (2 * w + 1) * 1024), 16, 0, 0);
  };

  stage(0);
  stage(1);
  stage(2);

#pragma unroll
  for (int s = 0; s < S; ++s) {
    const int rem = S - 1 - s;
    if (rem >= 2)      asm volatile("s_waitcnt vmcnt(8)" ::: "memory");
    else if (rem == 1) asm volatile("s_waitcnt vmcnt(4)" ::: "memory");
    else               asm volatile("s_waitcnt vmcnt(0)" ::: "memory");
    __builtin_amdgcn_s_barrier();
    char* buf = lds + (s % 3) * 16384;
    bf16x8 af[4], bfr[4];
#pragma unroll
    for (int i = 0; i < 4; ++i)
      af[i] = *reinterpret_cast<const bf16x8*>(buf + (wm * 4 + i) * 1024 + l * 16);
#pragma unroll
    for (int j = 0; j < 4; ++j)
      bfr[j] = *reinterpret_cast<const bf16x8*>(buf + 8192 + (wn * 4 + j) * 1024 + l * 16);
#pragma unroll
    for (int i = 0; i < 4; ++i)
#pragma unroll
      for (int j = 0; j < 4; ++j)
        acc[i][j] = __builtin_amdgcn_mfma_f32_16x16x32_bf16(af[i], bfr[j], acc[i][j], 0, 0, 0);
    asm volatile("s_waitcnt lgkmcnt(0)" ::: "memory");
    __builtin_amdgcn_s_barrier();
    if (s + 3 < S) stage(s + 3);
  }

#pragma unroll
  for (int j = 0; j < 4; ++j) {
    const int c = n0 + wn * 64 + j * 16 + l15;
    const float bv = bias[c];
#pragma unroll
    for (int i = 0; i < 4; ++i) {
      const int rowb = m0 + wm * 64 + i * 16 + l4 * 4;
#pragma unroll
      for (int r = 0; r < 4; ++r) {
        const int row = rowb + r;
        if (row < M) {
          float t = acc[i][j][r] + bv;
          if (RELU) t = fmaxf(t, 0.f);
          out[(size_t)row * DOUT + c] = f2bf(t);
        }
      }
    }
  }
}

// ---------------- loss (dec is COMPACT: NM x 128, slot m <-> node mask[m]) -------------
__global__ __launch_bounds__(256)
void k_loss1(const u16* __restrict__ dec, const float* __restrict__ attr,
             const int* __restrict__ mask, int NM, float* __restrict__ partials) {
  __shared__ float sm[256];
  float s = 0.f;
  const int total = NM * (IN_DIM / 4);
  for (int idx = blockIdx.x * blockDim.x + threadIdx.x; idx < total; idx += gridDim.x * blockDim.x) {
    const int m = idx >> 5, c = (idx & 31) * 4;
    const int node = mask[m];
    const float4 a = *reinterpret_cast<const float4*>(&attr[(size_t)node * IN_DIM + c]);
    const uint2 d2 = *reinterpret_cast<const uint2*>(&dec[(size_t)m * IN_DIM + c]);
    const float dx = bfu2f(d2.x & 0xffffu) - a.x;
    const float dy = bfu2f(d2.x >> 16)     - a.y;
    const float dz = bfu2f(d2.y & 0xffffu) - a.z;
    const float dw = bfu2f(d2.y >> 16)     - a.w;
    s += dx * dx + dy * dy + dz * dz + dw * dw;
  }
  sm[threadIdx.x] = s;
  __syncthreads();
  for (int off = 128; off > 0; off >>= 1) {
    if (threadIdx.x < off) sm[threadIdx.x] += sm[threadIdx.x + off];
    __syncthreads();
  }
  if (threadIdx.x == 0) partials[blockIdx.x] = sm[0];
}

__global__ __launch_bounds__(256)
void k_loss2(const float* __restrict__ partials, int nb, float* __restrict__ out, float inv) {
  __shared__ float sm[256];
  float s = 0.f;
  for (int i = threadIdx.x; i < nb; i += 256) s += partials[i];
  sm[threadIdx.x] = s;
  __syncthreads();
  for (int off = 128; off > 0; off >>= 1) {
    if (threadIdx.x < off) sm[threadIdx.x] += sm[threadIdx.x + off];
    __syncthreads();
  }
  if (threadIdx.x == 0) out[0] = sm[0] * inv;
}

// ---------------- launch ----------------
extern "C" void kernel_launch(void* const* d_in, const int* in_sizes, int n_in,
                              void* d_out, int out_size, void* d_ws, size_t ws_size,
                              hipStream_t stream) {
  const float* attr  = (const float*)d_in[0];
  const float* token = (const float*)d_in[1];
  const int*   src   = (const int*)d_in[2];
  const int*   dst   = (const int*)d_in[3];
  const int*   mask  = (const int*)d_in[4];
  const float* Wself[4]  = {(const float*)d_in[5], (const float*)d_in[8],
                            (const float*)d_in[11], (const float*)d_in[14]};
  const float* Wneigh[4] = {(const float*)d_in[6], (const float*)d_in[9],
                            (const float*)d_in[12], (const float*)d_in[15]};
  const float* Bias[4]   = {(const float*)d_in[7], (const float*)d_in[10],
                            (const float*)d_in[13], (const float*)d_in[16]};
  const int N  = in_sizes[0] / IN_DIM;
  const int E  = in_sizes[2];
  const int NM = in_sizes[4];

  size_t off = 0;
  auto take = [&](size_t bytes) -> void* {
    void* p = (char*)d_ws + off;
    off += (bytes + 255) & ~(size_t)255;
    return p;
  };
  u16* HA = (u16*)take((size_t)N * HID * sizeof(u16));   // 51.2 MB
  u16* HB = (u16*)take((size_t)N * HID * sizeof(u16));   // 51.2 MB
  const int dims_in[4]  = {IN_DIM, HID, HID, HID};
  const int dims_out[4] = {HID, HID, HID, IN_DIM};
  u16* WtS[4]; u16* WtN[4];
  for (int i = 0; i < 4; ++i) {
    WtS[i] = (u16*)take((size_t)dims_in[i] * dims_out[i] * sizeof(u16));
    WtN[i] = (u16*)take((size_t)dims_in[i] * dims_out[i] * sizeof(u16));
  }
  int* deg    = (int*)take((size_t)N * sizeof(int));
  int* rowptr = (int*)take((size_t)(N + 1) * sizeof(int));
  int* cursor = (int*)take((size_t)N * sizeof(int));
  int* col    = (int*)take((size_t)E * sizeof(int));
  int* bsum   = (int*)take(256 * sizeof(int));
  float* partials = (float*)take(512 * sizeof(float));

  // agg chunk: one chunk covering N (rounded to 256)
  size_t rem = (ws_size > off + 4096) ? (ws_size - off - 4096) : 0;
  const int cap = (int)(rem / ((size_t)HID * sizeof(u16)));
  const int want = (N + 255) & ~255;
  int chunk = (cap >= want) ? want : (cap & ~255);
  if (chunk < 2048) chunk = 2048;
  u16* CH = (u16*)take((size_t)chunk * HID * sizeof(u16));
  u16* DEC = HA;                               // decoded compact (NM x 128) reuses HA

  // CSR build (multi-block 3-phase scan; nb = ceil(N/2048) <= 256 for N <= 524288)
  k_zero<<<imin_h((N + 255) / 256, 1024), 256, 0, stream>>>(deg, N);
  const int eb = imin_h((E + 255) / 256, 4096);
  k_hist<<<eb, 256, 0, stream>>>(dst, deg, E);
  const int nb = (N + 2047) / 2048;
  k_scan1<<<nb, 256, 0, stream>>>(deg, bsum, N);
  k_scan2<<<1, 256, 0, stream>>>(bsum, nb, rowptr, N);
  k_scan3<<<nb, 256, 0, stream>>>(deg, bsum, rowptr, cursor, N);
  k_fill<<<eb, 256, 0, stream>>>(src, dst, cursor, col, E);

  // weights: transpose + bf16 + fragment-pack once per call
  for (int i = 0; i < 4; ++i) {
    const int tot = dims_in[i] * dims_out[i];
    k_wt<<<imin_h((tot + 255) / 256, 2048), 256, 0, stream>>>(Wself[i],  WtS[i], dims_in[i], dims_out[i]);
    k_wt<<<imin_h((tot + 255) / 256, 2048), 256, 0, stream>>>(Wneigh[i], WtN[i], dims_in[i], dims_out[i]);
  }

  // h0 = bf16(attr) with masked rows = token   (in HA as N x 128)
  const int n4 = N * (IN_DIM / 4);
  k_cvt<<<imin_h((n4 + 255) / 256, 2048), 256, 0, stream>>>((const float4*)attr, (uint2*)HA, n4);
  k_mask<<<imin_h((NM * (IN_DIM / 4) + 255) / 256, 2048), 256, 0, stream>>>(
      (const float4*)token, mask, (uint2*)HA, NM);

  // L1..L3 (full N, DOUT=512): agg chunk -> big gemm (128x256 tiles)
  auto run_layer = [&](const u16* hin, u16* hout, int din, int layer, bool relu) {
    for (int c0 = 0; c0 < N; c0 += chunk) {
      const int mc = imin_h(chunk, N - c0);
      const int ab = (mc + 3) / 4;
      if (din == IN_DIM)
        k_agg<IN_DIM, false><<<ab, 256, 0, stream>>>(hin, col, rowptr + c0, nullptr, CH, mc);
      else
        k_agg<HID, false><<<ab, 256, 0, stream>>>(hin, col, rowptr + c0, nullptr, CH, mc);
      const u16* a1 = hin + (size_t)c0 * din;
      u16* o = hout + (size_t)c0 * HID;
      const int mb = (mc + 127) / 128;
      if (din == IN_DIM && relu)
        k_gemm_big<IN_DIM, true><<<dim3(2, mb), 512, 0, stream>>>(
            a1, CH, WtS[layer], WtN[layer], Bias[layer], o, mc);
      else if (relu)
        k_gemm_big<HID, true><<<dim3(2, mb), 512, 0, stream>>>(
            a1, CH, WtS[layer], WtN[layer], Bias[layer], o, mc);
      else
        k_gemm_big<HID, false><<<dim3(2, mb), 512, 0, stream>>>(
            a1, CH, WtS[layer], WtN[layer], Bias[layer], o, mc);
    }
  };

  run_layer(HA, HB, IN_DIM, 0, true);   // L1: 128->512 relu   (HA h0 -> HB h1)
  run_layer(HB, HA, HID,    1, false);  // L2: 512->512        (HB h1 -> HA h2)
  run_layer(HA, HB, HID,    2, true);   // L3: 512->512 relu   (HA h2 -> HB h3)

  // L4 mask-restricted: decoded only at mask nodes (compact NM rows)
  k_agg<HID, true><<<(NM + 3) / 4, 256, 0, stream>>>(HB, col, rowptr, mask, CH, NM);
  k_gemm<HID, IN_DIM, false, true><<<dim3(1, (NM + 127) / 128), 256, 0, stream>>>(
      HB, CH, WtS[3], WtN[3], Bias[3], DEC, NM, mask);

  // loss = mean((decoded[mask] - attr[mask])^2)
  k_loss1<<<512, 256, 0, stream>>>(DEC, attr, mask, NM, partials);
  k_loss2<<<1, 256, 0, stream>>>(partials, 512, (float*)d_out, 1.0f / ((float)NM * IN_DIM));
}

// Round 13
// 455.607 us; speedup vs baseline: 1.6435x; 1.0020x over previous
//
#include <hip/hip_runtime.h>
#include <cstdint>
#include <cstddef>

#define IN_DIM 128
#define HID    512

typedef unsigned int   uint32;
typedef unsigned short u16;
typedef __attribute__((ext_vector_type(8))) short bf16x8;   // 8 bf16 (4 VGPRs)
typedef __attribute__((ext_vector_type(4))) float f32x4;

static inline int imin_h(int a, int b) { return a < b ? a : b; }

// ---- bf16 helpers (storage-only bf16; accumulation fp32) ----
__device__ __forceinline__ float bfu2f(uint32 u) { return __uint_as_float(u << 16); }
__device__ __forceinline__ u16 f2bf(float f) {
  uint32 x = __float_as_uint(f);
  x += 0x7fffu + ((x >> 16) & 1u);           // round-to-nearest-even
  return (u16)(x >> 16);
}
__device__ __forceinline__ uint32 pack2(float a, float b) {
  return (uint32)f2bf(a) | ((uint32)f2bf(b) << 16);
}

#define GLOBAL_AS(p) ((const __attribute__((address_space(1))) void*)(p))
#define LDS_AS(p)    ((__attribute__((address_space(3))) void*)(p))

// ---------------- misc ----------------
__global__ void k_zero(int* __restrict__ p, int n) {
  for (int i = blockIdx.x * blockDim.x + threadIdx.x; i < n; i += gridDim.x * blockDim.x)
    p[i] = 0;
}

// ---------------- CSR build (by dst) ----------------
__global__ void k_hist(const int* __restrict__ dst, int* __restrict__ deg, int E) {
  for (int e = blockIdx.x * blockDim.x + threadIdx.x; e < E; e += gridDim.x * blockDim.x)
    atomicAdd(&deg[dst[e]], 1);
}

// ---- 3-phase multi-block exclusive scan (chunk = 2048 = 256 thr x 8) ----
__global__ __launch_bounds__(256)
void k_scan1(const int* __restrict__ deg, int* __restrict__ bsum, int n) {
  __shared__ int sm[256];
  const int base = blockIdx.x * 2048 + threadIdx.x * 8;
  int s = 0;
  if (base + 8 <= n) {
    const uint4 a = *reinterpret_cast<const uint4*>(deg + base);
    const uint4 b = *reinterpret_cast<const uint4*>(deg + base + 4);
    s = (int)(a.x + a.y + a.z + a.w + b.x + b.y + b.z + b.w);
  } else {
    for (int i = 0; i < 8; ++i) if (base + i < n) s += deg[base + i];
  }
  sm[threadIdx.x] = s;
  __syncthreads();
  for (int off = 128; off > 0; off >>= 1) {
    if (threadIdx.x < off) sm[threadIdx.x] += sm[threadIdx.x + off];
    __syncthreads();
  }
  if (threadIdx.x == 0) bsum[blockIdx.x] = sm[0];
}

__global__ __launch_bounds__(256)
void k_scan2(int* __restrict__ bsum, int nb, int* __restrict__ rowptr, int n) {
  __shared__ int sm[256];
  const int v = (threadIdx.x < nb) ? bsum[threadIdx.x] : 0;
  sm[threadIdx.x] = v;
  __syncthreads();
  for (int off = 1; off < 256; off <<= 1) {
    const int t = (threadIdx.x >= off) ? sm[threadIdx.x - off] : 0;
    __syncthreads();
    sm[threadIdx.x] += t;
    __syncthreads();
  }
  if (threadIdx.x < nb) bsum[threadIdx.x] = sm[threadIdx.x] - v;  // exclusive
  if (threadIdx.x == nb - 1) rowptr[n] = sm[threadIdx.x];          // total = E
}

__global__ __launch_bounds__(256)
void k_scan3(const int* __restrict__ deg, const int* __restrict__ bsum,
             int* __restrict__ rowptr, int* __restrict__ cursor, int n) {
  __shared__ int sm[256];
  const int base = blockIdx.x * 2048 + threadIdx.x * 8;
  int v[8];
  int s = 0;
#pragma unroll
  for (int i = 0; i < 8; ++i) {
    v[i] = (base + i < n) ? deg[base + i] : 0;
    s += v[i];
  }
  sm[threadIdx.x] = s;
  __syncthreads();
  for (int off = 1; off < 256; off <<= 1) {
    const int t = (threadIdx.x >= off) ? sm[threadIdx.x - off] : 0;
    __syncthreads();
    sm[threadIdx.x] += t;
    __syncthreads();
  }
  int run = bsum[blockIdx.x] + sm[threadIdx.x] - s;   // exclusive prefix for this thread
#pragma unroll
  for (int i = 0; i < 8; ++i) {
    if (base + i < n) { rowptr[base + i] = run; cursor[base + i] = run; }
    run += v[i];
  }
}

__global__ void k_fill(const int* __restrict__ src, const int* __restrict__ dst,
                       int* __restrict__ cursor, int* __restrict__ col, int E) {
  for (int e = blockIdx.x * blockDim.x + threadIdx.x; e < E; e += gridDim.x * blockDim.x) {
    const int p = atomicAdd(&cursor[dst[e]], 1);
    col[p] = src[e];
  }
}

// ---------------- h0 = bf16(attr); masked rows = token ----------------
__global__ void k_cvt(const float4* __restrict__ in, uint2* __restrict__ out, int n4) {
  for (int i = blockIdx.x * blockDim.x + threadIdx.x; i < n4; i += gridDim.x * blockDim.x) {
    const float4 v = in[i];
    out[i] = make_uint2(pack2(v.x, v.y), pack2(v.z, v.w));
  }
}

__global__ void k_mask(const float4* __restrict__ token, const int* __restrict__ mask,
                       uint2* __restrict__ h0, int NM) {
  const int total = NM * (IN_DIM / 4);
  for (int i = blockIdx.x * blockDim.x + threadIdx.x; i < total; i += gridDim.x * blockDim.x) {
    const int m = i >> 5;
    const int c = i & 31;
    const float4 t = token[c];
    h0[(size_t)mask[m] * (IN_DIM / 4) + c] = make_uint2(pack2(t.x, t.y), pack2(t.z, t.w));
  }
}

// ------- weight transpose + convert + FRAGMENT-PACK ----------------------------------
// frag f = (n>>4)*(K/32) + (k>>5); u16 idx = f*512 + ((k>>3)&3)*128 + (n&15)*8 + (k&7).
__global__ void k_wt(const float* __restrict__ W, u16* __restrict__ Wt, int K, int Nn) {
  const int total = K * Nn;
  for (int t = blockIdx.x * blockDim.x + threadIdx.x; t < total; t += gridDim.x * blockDim.x) {
    const int n = t / K, k = t - n * K;
    const size_t idx = ((size_t)(n >> 4) * (K >> 5) + (k >> 5)) * 512 +
                       ((k >> 3) & 3) * 128 + ((n & 15) << 3) + (k & 7);
    Wt[idx] = f2bf(W[(size_t)k * Nn + n]);
  }
}

// -------- mean aggregation over in-neighbors (CSR gather, 1 wave/node, 2-deep) --------
template <int D, bool REMAP>
__global__ __launch_bounds__(256)
void k_agg(const u16* __restrict__ h, const int* __restrict__ col,
           const int* __restrict__ rowptr, const int* __restrict__ nodes,
           u16* __restrict__ out, int n) {
  constexpr int V = D / 64;
  const int w = blockIdx.x * (blockDim.x >> 6) + (threadIdx.x >> 6);
  if (w >= n) return;
  const int node = REMAP ? nodes[w] : w;
  const int lane = threadIdx.x & 63;
  const int beg = rowptr[node], end = rowptr[node + 1];
  const size_t loff = (size_t)lane * V;
  float acc[V];
#pragma unroll
  for (int j = 0; j < V; ++j) acc[j] = 0.f;
  if constexpr (V == 8) {
    uint4 cur;
    if (beg < end) cur = *reinterpret_cast<const uint4*>(h + (size_t)col[beg] * D + loff);
    for (int e = beg; e < end; ++e) {
      uint4 nxt = cur;
      if (e + 1 < end)
        nxt = *reinterpret_cast<const uint4*>(h + (size_t)col[e + 1] * D + loff);
      acc[0] += bfu2f(cur.x & 0xffffu); acc[1] += bfu2f(cur.x >> 16);
      acc[2] += bfu2f(cur.y & 0xffffu); acc[3] += bfu2f(cur.y >> 16);
      acc[4] += bfu2f(cur.z & 0xffffu); acc[5] += bfu2f(cur.z >> 16);
      acc[6] += bfu2f(cur.w & 0xffffu); acc[7] += bfu2f(cur.w >> 16);
      cur = nxt;
    }
  } else {
    uint32 cur = 0;
    if (beg < end) cur = *reinterpret_cast<const uint32*>(h + (size_t)col[beg] * D + loff);
    for (int e = beg; e < end; ++e) {
      uint32 nxt = cur;
      if (e + 1 < end)
        nxt = *reinterpret_cast<const uint32*>(h + (size_t)col[e + 1] * D + loff);
      acc[0] += bfu2f(cur & 0xffffu); acc[1] += bfu2f(cur >> 16);
      cur = nxt;
    }
  }
  const float inv = 1.0f / fmaxf((float)(end - beg), 1.0f);
  u16* o = out + (size_t)w * D + loff;
  if constexpr (V == 8) {
    uint4 u;
    u.x = pack2(acc[0] * inv, acc[1] * inv);
    u.y = pack2(acc[2] * inv, acc[3] * inv);
    u.z = pack2(acc[4] * inv, acc[5] * inv);
    u.w = pack2(acc[6] * inv, acc[7] * inv);
    *reinterpret_cast<uint4*>(o) = u;
  } else {
    *reinterpret_cast<uint32*>(o) = pack2(acc[0] * inv, acc[1] * inv);
  }
}

// ======== dual-A bf16 MFMA GEMM: 128x256 tile, 8 waves of 64x64, 2 blocks/CU ===========
// SINGLE-barrier K-loop (T3 minimal): vmcnt(3) -> barrier -> stage(s+2) -> ds_read+MFMA
// -> lgkmcnt(0).  stage(s+2) writes buf[(s-1)%3], whose reads were drained by every
// wave's lgkmcnt(0) before the step-s barrier (race-safe). 3 x 24KB LDS, 72KB total.
template <int DIN, bool RELU>
__global__ __launch_bounds__(512, 4)
void k_gemm_big(const u16* __restrict__ A1, const u16* __restrict__ A2,
                const u16* __restrict__ Wt1, const u16* __restrict__ Wt2,
                const float* __restrict__ bias, u16* __restrict__ out, int M) {
  constexpr int DOUT = HID;
  __shared__ char lds[73728];                 // 3 x (A 8KB + B 16KB); epilogue: 8 x 9216B
  constexpr int KS = DIN / 32;                // k-frags per phase
  constexpr int S  = 2 * KS;                  // total K-steps (dual-A)
  const int tid = threadIdx.x;
  const int w = tid >> 6, l = tid & 63;
  const int l15 = l & 15, l4 = l >> 4;
  const int wm = w >> 2, wn = w & 3;          // 2 x 4 wave grid, wave tile 64x64

  // bijective XCD swizzle (m204); n-tile fastest
  const int nwg  = gridDim.x * gridDim.y;
  const int orig = blockIdx.x + gridDim.x * blockIdx.y;
  const int q = nwg >> 3, r = nwg & 7;
  const int xcd = orig & 7, seq = orig >> 3;
  const int wg = (xcd < r ? xcd * (q + 1) : r * (q + 1) + (xcd - r) * q) + seq;
  const int mt = wg >> 1, nt = wg & 1;        // NT = 2
  const int m0 = mt * 128, n0 = nt * 256;

  f32x4 acc[4][4];
#pragma unroll
  for (int i = 0; i < 4; ++i)
#pragma unroll
    for (int j = 0; j < 4; ++j) acc[i][j] = (f32x4){0.f, 0.f, 0.f, 0.f};

  // A staging: wave w stages m-frag w (rows m0 + w*16 + l15)
  const int arow = min(m0 + w * 16 + l15, M - 1);
  const int kl = l4 * 8;
  const u16* pA1 = A1 + (size_t)arow * DIN + kl;
  const u16* pA2 = A2 + (size_t)arow * DIN + kl;
  // B staging (fragment-packed): wave w stages n-frags {2w, 2w+1}
  const u16* bb1 = Wt1 + ((size_t)(n0 >> 4) + 2 * w) * KS * 512 + (size_t)l * 8;
  const u16* bb2 = Wt2 + ((size_t)(n0 >> 4) + 2 * w) * KS * 512 + (size_t)l * 8;

  auto stage = [&](int s) {                    // 3 global_load_lds per wave
    const int ph = s / KS;
    const int kf = s - ph * KS;
    char* buf = lds + (s % 3) * 24576;
    const u16* a0 = (ph ? pA2 : pA1) + kf * 32;
    const u16* b0 = (ph ? bb2 : bb1) + kf * 512;
    const u16* b1 = b0 + KS * 512;             // next n-frag
    __builtin_amdgcn_global_load_lds(GLOBAL_AS(a0), LDS_AS(buf + w * 1024), 16, 0, 0);
    __builtin_amdgcn_global_load_lds(GLOBAL_AS(b0), LDS_AS(buf + 8192 + (2 * w + 0) * 1024), 16, 0, 0);
    __builtin_amdgcn_global_load_lds(GLOBAL_AS(b1), LDS_AS(buf + 8192 + (2 * w + 1) * 1024), 16, 0, 0);
  };

  stage(0);
  stage(1);

#pragma unroll
  for (int s = 0; s < S; ++s) {
    // own 3 loads for buf[s] done; next stage's 3 may stay in flight
    if (s + 1 < S) asm volatile("s_waitcnt vmcnt(3)" ::: "memory");
    else           asm volatile("s_waitcnt vmcnt(0)" ::: "memory");
    __builtin_amdgcn_s_barrier();
    if (s + 2 < S) stage(s + 2);               // refills buf[(s-1)%3] — drained pre-barrier
    char* buf = lds + (s % 3) * 24576;
    bf16x8 af[4], bfr[4];
#pragma unroll
    for (int i = 0; i < 4; ++i)
      af[i] = *reinterpret_cast<const bf16x8*>(buf + (wm * 4 + i) * 1024 + l * 16);
#pragma unroll
    for (int j = 0; j < 4; ++j)
      bfr[j] = *reinterpret_cast<const bf16x8*>(buf + 8192 + (wn * 4 + j) * 1024 + l * 16);
#pragma unroll
    for (int i = 0; i < 4; ++i)
#pragma unroll
      for (int j = 0; j < 4; ++j)
        acc[i][j] = __builtin_amdgcn_mfma_f32_16x16x32_bf16(af[i], bfr[j], acc[i][j], 0, 0, 0);
    asm volatile("s_waitcnt lgkmcnt(0)" ::: "memory");   // reads of buf retired
  }
  __builtin_amdgcn_s_barrier();                // epilogue reuses pipeline LDS

  // ---- coalesced epilogue: C/D (col=lane&15, row=(lane>>4)*4+reg) -> LDS -> global ----
  u16* eb = (u16*)(lds + w * 9216);
  float bv[4];
#pragma unroll
  for (int j = 0; j < 4; ++j) bv[j] = bias[n0 + wn * 64 + j * 16 + l15];
#pragma unroll
  for (int i = 0; i < 4; ++i)
#pragma unroll
    for (int j = 0; j < 4; ++j)
#pragma unroll
      for (int r = 0; r < 4; ++r) {
        const int lr = i * 16 + l4 * 4 + r;
        float t = acc[i][j][r] + bv[j];
        if (RELU) t = fmaxf(t, 0.f);
        eb[lr * 72 + j * 16 + l15] = f2bf(t);
      }
  asm volatile("s_waitcnt lgkmcnt(0)" ::: "memory");      // wave-local write->read order
#pragma unroll
  for (int p = 0; p < 8; ++p) {
    const int lr = p * 8 + (l >> 3);
    const int row = m0 + wm * 64 + lr;
    if (row < M) {
      const uint4 v = *reinterpret_cast<const uint4*>(eb + lr * 72 + (l & 7) * 8);
      *reinterpret_cast<uint4*>(out + (size_t)row * DOUT + n0 + wn * 64 + (l & 7) * 8) = v;
    }
  }
}

// -------- 128x128 4-wave kernel (DOUT=128, optional A1-row remap — L4) -----------------
// Same single-barrier pipeline (4 loads/wave/stage -> vmcnt(4/0)).
template <int DIN, int DOUT, bool RELU, bool REMAP>
__global__ __launch_bounds__(256, 3)
void k_gemm(const u16* __restrict__ A1, const u16* __restrict__ A2,
            const u16* __restrict__ Wt1, const u16* __restrict__ Wt2,
            const float* __restrict__ bias, u16* __restrict__ out, int M,
            const int* __restrict__ remap) {
  __shared__ char lds[49152];
  constexpr int KS = DIN / 32;
  constexpr int S  = 2 * KS;
  const int tid = threadIdx.x;
  const int w = tid >> 6, l = tid & 63;
  const int l15 = l & 15, l4 = l >> 4;
  const int wm = w >> 1, wn = w & 1;

  const int nwg  = gridDim.x * gridDim.y;
  const int orig = blockIdx.x + gridDim.x * blockIdx.y;
  const int q = nwg >> 3, r = nwg & 7;
  const int xcd = orig & 7, seq = orig >> 3;
  const int wg = (xcd < r ? xcd * (q + 1) : r * (q + 1) + (xcd - r) * q) + seq;
  constexpr int NT = DOUT / 128;
  const int mt = wg / NT, nt = wg - mt * NT;
  const int m0 = mt * 128, n0 = nt * 128;

  f32x4 acc[4][4];
#pragma unroll
  for (int i = 0; i < 4; ++i)
#pragma unroll
    for (int j = 0; j < 4; ++j) acc[i][j] = (f32x4){0.f, 0.f, 0.f, 0.f};

  const int am0 = min(m0 + (2 * w) * 16 + l15, M - 1);
  const int am1 = min(m0 + (2 * w + 1) * 16 + l15, M - 1);
  const int ar0 = REMAP ? remap[am0] : am0;
  const int ar1 = REMAP ? remap[am1] : am1;
  const int kl = l4 * 8;
  const u16* pA1r0 = A1 + (size_t)ar0 * DIN + kl;
  const u16* pA1r1 = A1 + (size_t)ar1 * DIN + kl;
  const u16* pA2r0 = A2 + (size_t)am0 * DIN + kl;
  const u16* pA2r1 = A2 + (size_t)am1 * DIN + kl;
  const u16* bb1 = Wt1 + ((size_t)(n0 >> 4) + 2 * w) * KS * 512 + (size_t)l * 8;
  const u16* bb2 = Wt2 + ((size_t)(n0 >> 4) + 2 * w) * KS * 512 + (size_t)l * 8;

  auto stage = [&](int s) {
    const int ph = s / KS;
    const int kf = s - ph * KS;
    char* buf = lds + (s % 3) * 16384;
    const u16* a0 = (ph ? pA2r0 : pA1r0) + kf * 32;
    const u16* a1 = (ph ? pA2r1 : pA1r1) + kf * 32;
    const u16* b0 = (ph ? bb2 : bb1) + kf * 512;
    const u16* b1 = b0 + KS * 512;
    __builtin_amdgcn_global_load_lds(GLOBAL_AS(a0), LDS_AS(buf + (2 * w + 0) * 1024), 16, 0, 0);
    __builtin_amdgcn_global_load_lds(GLOBAL_AS(a1), LDS_AS(buf + (2 * w + 1) * 1024), 16, 0, 0);
    __builtin_amdgcn_global_load_lds(GLOBAL_AS(b0), LDS_AS(buf + 8192 + (2 * w + 0) * 1024), 16, 0, 0);
    __builtin_amdgcn_global_load_lds(GLOBAL_AS(b1), LDS_AS(buf + 8192 + (2 * w + 1) * 1024), 16, 0, 0);
  };

  stage(0);
  stage(1);

#pragma unroll
  for (int s = 0; s < S; ++s) {
    if (s + 1 < S) asm volatile("s_waitcnt vmcnt(4)" ::: "memory");
    else           asm volatile("s_waitcnt vmcnt(0)" ::: "memory");
    __builtin_amdgcn_s_barrier();
    if (s + 2 < S) stage(s + 2);
    char* buf = lds + (s % 3) * 16384;
    bf16x8 af[4], bfr[4];
#pragma unroll
    for (int i = 0; i < 4; ++i)
      af[i] = *reinterpret_cast<const bf16x8*>(buf + (wm * 4 + i) * 1024 + l * 16);
#pragma unroll
    for (int j = 0; j < 4; ++j)
      bfr[j] = *reinterpret_cast<const bf16x8*>(buf + 8192 + (wn * 4 + j) * 1024 + l * 16);
#pragma unroll
    for (int i = 0; i < 4; ++i)
#pragma unroll
      for (int j = 0; j < 4; ++j)
        acc[i][j] = __builtin_amdgcn_mfma_f32_16x16x32_bf16(af[i], bfr[j], acc[i][j], 0, 0, 0);
    asm volatile("s_waitcnt lgkmcnt(0)" ::: "memory");
  }

#pragma unroll
  for (int j = 0; j < 4; ++j) {
    const int c = n0 + wn * 64 + j * 16 + l15;
    const float bv = bias[c];
#pragma unroll
    for (int i = 0; i < 4; ++i) {
      const int rowb = m0 + wm * 64 + i * 16 + l4 * 4;
#pragma unroll
      for (int r = 0; r < 4; ++r) {
        const int row = rowb + r;
        if (row < M) {
          float t = acc[i][j][r] + bv;
          if (RELU) t = fmaxf(t, 0.f);
          out[(size_t)row * DOUT + c] = f2bf(t);
        }
      }
    }
  }
}

// ---------------- loss (dec is COMPACT: NM x 128, slot m <-> node mask[m]) -------------
__global__ __launch_bounds__(256)
void k_loss1(const u16* __restrict__ dec, const float* __restrict__ attr,
             const int* __restrict__ mask, int NM, float* __restrict__ partials) {
  __shared__ float sm[256];
  float s = 0.f;
  const int total = NM * (IN_DIM / 4);
  for (int idx = blockIdx.x * blockDim.x + threadIdx.x; idx < total; idx += gridDim.x * blockDim.x) {
    const int m = idx >> 5, c = (idx & 31) * 4;
    const int node = mask[m];
    const float4 a = *reinterpret_cast<const float4*>(&attr[(size_t)node * IN_DIM + c]);
    const uint2 d2 = *reinterpret_cast<const uint2*>(&dec[(size_t)m * IN_DIM + c]);
    const float dx = bfu2f(d2.x & 0xffffu) - a.x;
    const float dy = bfu2f(d2.x >> 16)     - a.y;
    const float dz = bfu2f(d2.y & 0xffffu) - a.z;
    const float dw = bfu2f(d2.y >> 16)     - a.w;
    s += dx * dx + dy * dy + dz * dz + dw * dw;
  }
  sm[threadIdx.x] = s;
  __syncthreads();
  for (int off = 128; off > 0; off >>= 1) {
    if (threadIdx.x < off) sm[threadIdx.x] += sm[threadIdx.x + off];
    __syncthreads();
  }
  if (threadIdx.x == 0) partials[blockIdx.x] = sm[0];
}

__global__ __launch_bounds__(256)
void k_loss2(const float* __restrict__ partials, int nb, float* __restrict__ out, float inv) {
  __shared__ float sm[256];
  float s = 0.f;
  for (int i = threadIdx.x; i < nb; i += 256) s += partials[i];
  sm[threadIdx.x] = s;
  __syncthreads();
  for (int off = 128; off > 0; off >>= 1) {
    if (threadIdx.x < off) sm[threadIdx.x] += sm[threadIdx.x + off];
    __syncthreads();
  }
  if (threadIdx.x == 0) out[0] = sm[0] * inv;
}

// ---------------- launch ----------------
extern "C" void kernel_launch(void* const* d_in, const int* in_sizes, int n_in,
                              void* d_out, int out_size, void* d_ws, size_t ws_size,
                              hipStream_t stream) {
  const float* attr  = (const float*)d_in[0];
  const float* token = (const float*)d_in[1];
  const int*   src   = (const int*)d_in[2];
  const int*   dst   = (const int*)d_in[3];
  const int*   mask  = (const int*)d_in[4];
  const float* Wself[4]  = {(const float*)d_in[5], (const float*)d_in[8],
                            (const float*)d_in[11], (const float*)d_in[14]};
  const float* Wneigh[4] = {(const float*)d_in[6], (const float*)d_in[9],
                            (const float*)d_in[12], (const float*)d_in[15]};
  const float* Bias[4]   = {(const float*)d_in[7], (const float*)d_in[10],
                            (const float*)d_in[13], (const float*)d_in[16]};
  const int N  = in_sizes[0] / IN_DIM;
  const int E  = in_sizes[2];
  const int NM = in_sizes[4];

  size_t off = 0;
  auto take = [&](size_t bytes) -> void* {
    void* p = (char*)d_ws + off;
    off += (bytes + 255) & ~(size_t)255;
    return p;
  };
  u16* HA = (u16*)take((size_t)N * HID * sizeof(u16));   // 51.2 MB
  u16* HB = (u16*)take((size_t)N * HID * sizeof(u16));   // 51.2 MB
  const int dims_in[4]  = {IN_DIM, HID, HID, HID};
  const int dims_out[4] = {HID, HID, HID, IN_DIM};
  u16* WtS[4]; u16* WtN[4];
  for (int i = 0; i < 4; ++i) {
    WtS[i] = (u16*)take((size_t)dims_in[i] * dims_out[i] * sizeof(u16));
    WtN[i] = (u16*)take((size_t)dims_in[i] * dims_out[i] * sizeof(u16));
  }
  int* deg    = (int*)take((size_t)N * sizeof(int));
  int* rowptr = (int*)take((size_t)(N + 1) * sizeof(int));
  int* cursor = (int*)take((size_t)N * sizeof(int));
  int* col    = (int*)take((size_t)E * sizeof(int));
  int* bsum   = (int*)take(256 * sizeof(int));
  float* partials = (float*)take(512 * sizeof(float));

  // agg chunk: one chunk covering N (rounded to 256)
  size_t rem = (ws_size > off + 4096) ? (ws_size - off - 4096) : 0;
  const int cap = (int)(rem / ((size_t)HID * sizeof(u16)));
  const int want = (N + 255) & ~255;
  int chunk = (cap >= want) ? want : (cap & ~255);
  if (chunk < 2048) chunk = 2048;
  u16* CH = (u16*)take((size_t)chunk * HID * sizeof(u16));
  u16* DEC = HA;                               // decoded compact (NM x 128) reuses HA

  // CSR build (multi-block 3-phase scan)
  k_zero<<<imin_h((N + 255) / 256, 1024), 256, 0, stream>>>(deg, N);
  const int eb = imin_h((E + 255) / 256, 4096);
  k_hist<<<eb, 256, 0, stream>>>(dst, deg, E);
  const int nb = (N + 2047) / 2048;
  k_scan1<<<nb, 256, 0, stream>>>(deg, bsum, N);
  k_scan2<<<1, 256, 0, stream>>>(bsum, nb, rowptr, N);
  k_scan3<<<nb, 256, 0, stream>>>(deg, bsum, rowptr, cursor, N);
  k_fill<<<eb, 256, 0, stream>>>(src, dst, cursor, col, E);

  // weights: transpose + bf16 + fragment-pack once per call
  for (int i = 0; i < 4; ++i) {
    const int tot = dims_in[i] * dims_out[i];
    k_wt<<<imin_h((tot + 255) / 256, 2048), 256, 0, stream>>>(Wself[i],  WtS[i], dims_in[i], dims_out[i]);
    k_wt<<<imin_h((tot + 255) / 256, 2048), 256, 0, stream>>>(Wneigh[i], WtN[i], dims_in[i], dims_out[i]);
  }

  // h0 = bf16(attr) with masked rows = token   (in HA as N x 128)
  const int n4 = N * (IN_DIM / 4);
  k_cvt<<<imin_h((n4 + 255) / 256, 2048), 256, 0, stream>>>((const float4*)attr, (uint2*)HA, n4);
  k_mask<<<imin_h((NM * (IN_DIM / 4) + 255) / 256, 2048), 256, 0, stream>>>(
      (const float4*)token, mask, (uint2*)HA, NM);

  // L1..L3 (full N, DOUT=512): agg chunk -> big gemm (128x256 tiles)
  auto run_layer = [&](const u16* hin, u16* hout, int din, int layer, bool relu) {
    for (int c0 = 0; c0 < N; c0 += chunk) {
      const int mc = imin_h(chunk, N - c0);
      const int ab = (mc + 3) / 4;
      if (din == IN_DIM)
        k_agg<IN_DIM, false><<<ab, 256, 0, stream>>>(hin, col, rowptr + c0, nullptr, CH, mc);
      else
        k_agg<HID, false><<<ab, 256, 0, stream>>>(hin, col, rowptr + c0, nullptr, CH, mc);
      const u16* a1 = hin + (size_t)c0 * din;
      u16* o = hout + (size_t)c0 * HID;
      const int mb = (mc + 127) / 128;
      if (din == IN_DIM && relu)
        k_gemm_big<IN_DIM, true><<<dim3(2, mb), 512, 0, stream>>>(
            a1, CH, WtS[layer], WtN[layer], Bias[layer], o, mc);
      else if (relu)
        k_gemm_big<HID, true><<<dim3(2, mb), 512, 0, stream>>>(
            a1, CH, WtS[layer], WtN[layer], Bias[layer], o, mc);
      else
        k_gemm_big<HID, false><<<dim3(2, mb), 512, 0, stream>>>(
            a1, CH, WtS[layer], WtN[layer], Bias[layer], o, mc);
    }
  };

  run_layer(HA, HB, IN_DIM, 0, true);   // L1: 128->512 relu   (HA h0 -> HB h1)
  run_layer(HB, HA, HID,    1, false);  // L2: 512->512        (HB h1 -> HA h2)
  run_layer(HA, HB, HID,    2, true);   // L3: 512->512 relu   (HA h2 -> HB h3)

  // L4 mask-restricted: decoded only at mask nodes (compact NM rows)
  k_agg<HID, true><<<(NM + 3) / 4, 256, 0, stream>>>(HB, col, rowptr, mask, CH, NM);
  k_gemm<HID, IN_DIM, false, true><<<dim3(1, (NM + 127) / 128), 256, 0, stream>>>(
      HB, CH, WtS[3], WtN[3], Bias[3], DEC, NM, mask);

  // loss = mean((decoded[mask] - attr[mask])^2)
  k_loss1<<<512, 256, 0, stream>>>(DEC, attr, mask, NM, partials);
  k_loss2<<<1, 256, 0, stream>>>(partials, 512, (float*)d_out, 1.0f / ((float)NM * IN_DIM));
}